// Round 5
// baseline (2588.161 us; speedup 1.0000x reference)
//
#include <hip/hip_runtime.h>

#define PI_F 3.14159265358979323846f

struct Geom { float enc[8]; float h0, h1, h2; };

__device__ __forceinline__ bool geom_of(const float* __restrict__ r, int e, Geom& g) {
  const float rx = r[3*e], ry = r[3*e+1], rz = r[3*e+2];
  const float xsq = (rx*rx + ry*ry + rz*rz) * (1.0f/2.5f);
  const float cut = 1.0f - xsq;
  if (cut <= 0.0f) return false;
  const float c1 = cosf(PI_F * sqrtf(xsq));
  g.enc[0] = cut; g.enc[1] = c1*cut;
  float cp = 1.0f, cc = c1;
  #pragma unroll
  for (int n = 2; n < 8; n++) { float cn = 2.0f*c1*cc - cp; cp = cc; cc = cn; g.enc[n] = cn*cut; }
  const float s = 7.0f/2.5f;
  const float yx = rx*s, yy = ry*s, yz = rz*s;
  const float inv = rsqrtf(1.0f + yx*yx + yy*yy + yz*yz);
  g.h0 = yx*inv; g.h1 = yy*inv; g.h2 = yz*inv;
  return true;
}

__device__ __forceinline__ int edge_at(const int* __restrict__ cnt, const int* __restrict__ list,
                                       int idx, int E) {
  if (list) { if (idx >= *cnt) return -1; return list[idx]; }
  return idx < E ? idx : -1;
}

__global__ __launch_bounds__(256) void compact_k(const float* __restrict__ r, int E,
                                                 int* __restrict__ cnt, int* __restrict__ list) {
  int e = blockIdx.x * 256 + threadIdx.x;
  if (e >= E) return;
  float rx = r[3*e], ry = r[3*e+1], rz = r[3*e+2];
  float xsq = (rx*rx + ry*ry + rz*rz) * (1.0f/2.5f);
  if (xsq < 1.0f) {
    int p = atomicAdd(cnt, 1);
    list[p] = e;
  }
}

// c[56] = [xa(32) | s1 = h.xv (16) | s2 = h^T xd h (8)]
__device__ __forceinline__ void build_c(const float* __restrict__ x_a, const float* __restrict__ x_v,
                                        const float* __restrict__ x_d, int nj, const Geom& g,
                                        float (&c)[56]) {
  const float4* xa4 = (const float4*)(x_a + (size_t)nj*32);
  const float4* xv4 = (const float4*)(x_v + (size_t)nj*48);
  const float*  xd  = x_d + (size_t)nj*72;
  #pragma unroll
  for (int q = 0; q < 8; q++) { float4 f = xa4[q]; c[4*q]=f.x; c[4*q+1]=f.y; c[4*q+2]=f.z; c[4*q+3]=f.w; }
  #pragma unroll
  for (int q = 0; q < 4; q++) {
    float4 f0 = xv4[3*q], f1 = xv4[3*q+1], f2 = xv4[3*q+2];
    c[32+4*q+0] = g.h0*f0.x + g.h1*f0.y + g.h2*f0.z;
    c[32+4*q+1] = g.h0*f0.w + g.h1*f1.x + g.h2*f1.y;
    c[32+4*q+2] = g.h0*f1.z + g.h1*f1.w + g.h2*f2.x;
    c[32+4*q+3] = g.h0*f2.y + g.h1*f2.z + g.h2*f2.w;
  }
  #pragma unroll
  for (int b = 0; b < 8; b++) {
    const float* m = xd + 9*b;
    float t0 = g.h0*m[0] + g.h1*m[3] + g.h2*m[6];
    float t1 = g.h0*m[1] + g.h1*m[4] + g.h2*m[7];
    float t2 = g.h0*m[2] + g.h1*m[5] + g.h2*m[8];
    c[48+b] = g.h0*t0 + g.h1*t1 + g.h2*t2;
  }
}

// ---------------- rank-0: 2 edges/thread, packed LDS rows [a][l][56] ----------------
__global__ __launch_bounds__(256, 3) void msgA_k(
    const float* __restrict__ r_ij, const float* __restrict__ x_a,
    const float* __restrict__ x_v,  const float* __restrict__ x_d,
    const float* __restrict__ P000, const float* __restrict__ P110, const float* __restrict__ P220,
    const int* __restrict__ src, const int* __restrict__ dst,
    const int* __restrict__ cnt, const int* __restrict__ list, int E,
    float* __restrict__ outA)
{
  if (list && blockIdx.x * 512 >= *cnt) return;
  __shared__ float sP[32*8*56];          // 57.3 KB
  {
    float4* s4 = (float4*)sP;
    for (int i = threadIdx.x; i < 32*8*14; i += 256) {
      int row = i / 14, q = i - row*14;  // row = a*8+l
      float4 v;
      if (q < 8)       v = ((const float4*)P000)[row*8 + q];
      else if (q < 12) v = ((const float4*)P110)[row*4 + (q-8)];
      else             v = ((const float4*)P220)[row*2 + (q-12)];
      s4[i] = v;
    }
  }
  __syncthreads();

  const int i0 = blockIdx.x*512 + threadIdx.x;
  const int i1 = i0 + 256;
  const int e0 = edge_at(cnt, list, i0, E);
  const int e1 = edge_at(cnt, list, i1, E);
  Geom g0 = {}, g1 = {};
  const bool ok0 = (e0 >= 0) && geom_of(r_ij, e0, g0);
  const bool ok1 = (e1 >= 0) && geom_of(r_ij, e1, g1);
  if (!ok0 && !ok1) return;
  const int nj0 = ok0 ? dst[e0] : 0;
  const int nj1 = ok1 ? dst[e1] : 0;
  float c0[56], c1[56];
  build_c(x_a, x_v, x_d, nj0, g0, c0);
  build_c(x_a, x_v, x_d, nj1, g1, c1);
  float* o0 = outA + (size_t)(ok0 ? src[e0] : 0) * 32;
  float* o1 = outA + (size_t)(ok1 ? src[e1] : 0) * 32;

  #pragma unroll 1
  for (int a = 0; a < 32; a++) {
    float acc0 = 0.f, acc1 = 0.f;
    #pragma unroll
    for (int l = 0; l < 8; l++) {
      const float4* p = (const float4*)(sP + (a*8 + l)*56);
      float u00=0,u01=0,u02=0,u03=0, u10=0,u11=0,u12=0,u13=0;
      #pragma unroll
      for (int q = 0; q < 14; q++) {
        const float4 f = p[q];
        u00 += f.x*c0[4*q+0]; u01 += f.y*c0[4*q+1]; u02 += f.z*c0[4*q+2]; u03 += f.w*c0[4*q+3];
        u10 += f.x*c1[4*q+0]; u11 += f.y*c1[4*q+1]; u12 += f.z*c1[4*q+2]; u13 += f.w*c1[4*q+3];
      }
      acc0 += g0.enc[l]*((u00+u01)+(u02+u03));
      acc1 += g1.enc[l]*((u10+u11)+(u12+u13));
    }
    if (ok0) atomicAdd(o0 + a, 0.1f*acc0);
    if (ok1) atomicAdd(o1 + a, 0.1f*acc1);
  }
}

// ---------------- rank-1: 1 edge/thread, packed rows [v][l][P011|P121|P111|P101|P211] (88) ----------------
__global__ __launch_bounds__(256, 3) void msgV_k(
    const float* __restrict__ r_ij, const float* __restrict__ x_a,
    const float* __restrict__ x_v,  const float* __restrict__ x_d,
    const float* __restrict__ P011, const float* __restrict__ P101, const float* __restrict__ P121,
    const float* __restrict__ P211, const float* __restrict__ P111,
    const int* __restrict__ src, const int* __restrict__ dst,
    const int* __restrict__ cnt, const int* __restrict__ list, int E,
    float* __restrict__ outV)
{
  if (list && blockIdx.x * 256 >= *cnt) return;
  __shared__ float sP[16*8*88];          // 45 KB
  {
    float4* s4 = (float4*)sP;
    for (int i = threadIdx.x; i < 16*8*22; i += 256) {
      int row = i / 22, q = i - row*22;  // row = v*8+l
      float4 v;
      if (q < 4)       v = ((const float4*)P011)[row*4 + q];
      else if (q < 6)  v = ((const float4*)P121)[row*2 + (q-4)];
      else if (q < 10) v = ((const float4*)P111)[row*4 + (q-6)];
      else if (q < 18) v = ((const float4*)P101)[row*8 + (q-10)];
      else             v = ((const float4*)P211)[row*4 + (q-18)];
      s4[i] = v;
    }
  }
  __syncthreads();

  const int idx = blockIdx.x*256 + threadIdx.x;
  const int e = edge_at(cnt, list, idx, E);
  if (e < 0) return;
  Geom g;
  if (!geom_of(r_ij, e, g)) return;
  const int nj = dst[e], ni = src[e];

  float xs[48];                       // [xa | s1]
  {
    const float4* xa4 = (const float4*)(x_a + (size_t)nj*32);
    #pragma unroll
    for (int q = 0; q < 8; q++) { float4 f = xa4[q]; xs[4*q]=f.x; xs[4*q+1]=f.y; xs[4*q+2]=f.z; xs[4*q+3]=f.w; }
  }
  float Y0[24], Y1[24], Y2[24];       // [V | T]
  {
    const float4* xv4 = (const float4*)(x_v + (size_t)nj*48);
    #pragma unroll
    for (int q = 0; q < 4; q++) {
      float4 f0 = xv4[3*q], f1 = xv4[3*q+1], f2 = xv4[3*q+2];
      Y0[4*q+0]=f0.x; Y1[4*q+0]=f0.y; Y2[4*q+0]=f0.z;
      Y0[4*q+1]=f0.w; Y1[4*q+1]=f1.x; Y2[4*q+1]=f1.y;
      Y0[4*q+2]=f1.z; Y1[4*q+2]=f1.w; Y2[4*q+2]=f2.x;
      Y0[4*q+3]=f2.y; Y1[4*q+3]=f2.z; Y2[4*q+3]=f2.w;
    }
    const float* xd = x_d + (size_t)nj*72;
    #pragma unroll
    for (int b = 0; b < 8; b++) {
      const float* m = xd + 9*b;
      Y0[16+b] = g.h0*m[0] + g.h1*m[3] + g.h2*m[6];
      Y1[16+b] = g.h0*m[1] + g.h1*m[4] + g.h2*m[7];
      Y2[16+b] = g.h0*m[2] + g.h1*m[5] + g.h2*m[8];
    }
    #pragma unroll
    for (int b = 0; b < 16; b++)
      xs[32+b] = g.h0*Y0[b] + g.h1*Y1[b] + g.h2*Y2[b];
  }

  float* o = outV + (size_t)ni*48;
  #pragma unroll 1
  for (int v = 0; v < 16; v++) {
    const float* row0 = sP + v*8*88;
    float sv = 0.f;
    #pragma unroll
    for (int l = 0; l < 8; l++) {
      const float4* p = (const float4*)(row0 + l*88 + 40);
      float u0=0,u1=0,u2=0,u3=0;
      #pragma unroll
      for (int q = 0; q < 12; q++) {
        const float4 f = p[q];
        u0 += f.x*xs[4*q]; u1 += f.y*xs[4*q+1]; u2 += f.z*xs[4*q+2]; u3 += f.w*xs[4*q+3];
      }
      sv += g.enc[l]*((u0+u1)+(u2+u3));
    }
    float A0=0,A1=0,A2=0;
    #pragma unroll
    for (int j = 0; j < 6; j++) {
      float w0=0,w1=0,w2=0,w3=0;
      #pragma unroll
      for (int l = 0; l < 8; l++) {
        const float4 f = *(const float4*)(row0 + l*88 + 4*j);
        const float el = g.enc[l];
        w0 += el*f.x; w1 += el*f.y; w2 += el*f.z; w3 += el*f.w;
      }
      A0 += w0*Y0[4*j]+w1*Y0[4*j+1]+w2*Y0[4*j+2]+w3*Y0[4*j+3];
      A1 += w0*Y1[4*j]+w1*Y1[4*j+1]+w2*Y1[4*j+2]+w3*Y1[4*j+3];
      A2 += w0*Y2[4*j]+w1*Y2[4*j+1]+w2*Y2[4*j+2]+w3*Y2[4*j+3];
    }
    float W0=0,W1=0,W2=0;
    #pragma unroll
    for (int j = 0; j < 4; j++) {
      float w0=0,w1=0,w2=0,w3=0;
      #pragma unroll
      for (int l = 0; l < 8; l++) {
        const float4 f = *(const float4*)(row0 + l*88 + 24 + 4*j);
        const float el = g.enc[l];
        w0 += el*f.x; w1 += el*f.y; w2 += el*f.z; w3 += el*f.w;
      }
      W0 += w0*Y0[4*j]+w1*Y0[4*j+1]+w2*Y0[4*j+2]+w3*Y0[4*j+3];
      W1 += w0*Y1[4*j]+w1*Y1[4*j+1]+w2*Y1[4*j+2]+w3*Y1[4*j+3];
      W2 += w0*Y2[4*j]+w1*Y2[4*j+1]+w2*Y2[4*j+2]+w3*Y2[4*j+3];
    }
    atomicAdd(o + v*3 + 0, 0.1f*(A0 + (g.h1*W2 - g.h2*W1) + g.h0*sv));
    atomicAdd(o + v*3 + 1, 0.1f*(A1 + (g.h2*W0 - g.h0*W2) + g.h1*sv));
    atomicAdd(o + v*3 + 2, 0.1f*(A2 + (g.h0*W1 - g.h1*W0) + g.h2*sv));
  }
}

// ---------------- rank-2: 1 edge/thread, packed rows [d][l][P022|P222|P112|P212|P202] (80) ----------------
__global__ __launch_bounds__(256, 3) void msgD_k(
    const float* __restrict__ r_ij, const float* __restrict__ x_a,
    const float* __restrict__ x_v,  const float* __restrict__ x_d,
    const float* __restrict__ P022, const float* __restrict__ P202, const float* __restrict__ P112,
    const float* __restrict__ P222, const float* __restrict__ P212,
    const int* __restrict__ src, const int* __restrict__ dst,
    const int* __restrict__ cnt, const int* __restrict__ list, int E,
    float* __restrict__ outD)
{
  if (list && blockIdx.x * 256 >= *cnt) return;
  __shared__ float sP[8*8*80];           // 20.5 KB
  {
    float4* s4 = (float4*)sP;
    for (int i = threadIdx.x; i < 8*8*20; i += 256) {
      int row = i / 20, q = i - row*20;  // row = d*8+l
      float4 v;
      if (q < 2)       v = ((const float4*)P022)[row*2 + q];
      else if (q < 4)  v = ((const float4*)P222)[row*2 + (q-2)];
      else if (q < 8)  v = ((const float4*)P112)[row*4 + (q-4)];
      else if (q < 12) v = ((const float4*)P212)[row*4 + (q-8)];
      else             v = ((const float4*)P202)[row*8 + (q-12)];
      s4[i] = v;
    }
  }
  __syncthreads();

  const int idx = blockIdx.x*256 + threadIdx.x;
  const int e = edge_at(cnt, list, idx, E);
  if (e < 0) return;
  Geom g;
  if (!geom_of(r_ij, e, g)) return;
  const int nj = dst[e], ni = src[e];

  float xa[32];
  {
    const float4* xa4 = (const float4*)(x_a + (size_t)nj*32);
    #pragma unroll
    for (int q = 0; q < 8; q++) { float4 f = xa4[q]; xa[4*q]=f.x; xa[4*q+1]=f.y; xa[4*q+2]=f.z; xa[4*q+3]=f.w; }
  }
  float Y0[24], Y1[24], Y2[24];          // [V | T]
  {
    const float4* xv4 = (const float4*)(x_v + (size_t)nj*48);
    #pragma unroll
    for (int q = 0; q < 4; q++) {
      float4 f0 = xv4[3*q], f1 = xv4[3*q+1], f2 = xv4[3*q+2];
      Y0[4*q+0]=f0.x; Y1[4*q+0]=f0.y; Y2[4*q+0]=f0.z;
      Y0[4*q+1]=f0.w; Y1[4*q+1]=f1.x; Y2[4*q+1]=f1.y;
      Y0[4*q+2]=f1.z; Y1[4*q+2]=f1.w; Y2[4*q+2]=f2.x;
      Y0[4*q+3]=f2.y; Y1[4*q+3]=f2.z; Y2[4*q+3]=f2.w;
    }
    const float* xd = x_d + (size_t)nj*72;
    #pragma unroll
    for (int b = 0; b < 8; b++) {
      const float* m = xd + 9*b;
      Y0[16+b] = g.h0*m[0] + g.h1*m[3] + g.h2*m[6];
      Y1[16+b] = g.h0*m[1] + g.h1*m[4] + g.h2*m[7];
      Y2[16+b] = g.h0*m[2] + g.h1*m[5] + g.h2*m[8];
    }
  }
  const float4* xd4 = (const float4*)(x_d + (size_t)nj*72);
  float* o = outD + (size_t)ni*72;
  const float hh0 = g.h0, hh1 = g.h1, hh2 = g.h2;

  #pragma unroll 1
  for (int d = 0; d < 8; d++) {
    const float* row0 = sP + d*8*80;
    // scd
    float sd = 0.f;
    #pragma unroll
    for (int l = 0; l < 8; l++) {
      const float4* p = (const float4*)(row0 + l*80 + 48);
      float u0=0,u1=0,u2=0,u3=0;
      #pragma unroll
      for (int q = 0; q < 8; q++) {
        const float4 f = p[q];
        u0 += f.x*xa[4*q]; u1 += f.y*xa[4*q+1]; u2 += f.z*xa[4*q+2]; u3 += f.w*xa[4*q+3];
      }
      sd += g.enc[l]*((u0+u1)+(u2+u3));
    }
    // A-part: P112 (V) + P222 (T)
    float A0=0,A1=0,A2=0;
    #pragma unroll
    for (int j = 0; j < 4; j++) {
      float w0=0,w1=0,w2=0,w3=0;
      #pragma unroll
      for (int l = 0; l < 8; l++) {
        const float4 f = *(const float4*)(row0 + l*80 + 16 + 4*j);
        const float el = g.enc[l];
        w0 += el*f.x; w1 += el*f.y; w2 += el*f.z; w3 += el*f.w;
      }
      A0 += w0*Y0[4*j]+w1*Y0[4*j+1]+w2*Y0[4*j+2]+w3*Y0[4*j+3];
      A1 += w0*Y1[4*j]+w1*Y1[4*j+1]+w2*Y1[4*j+2]+w3*Y1[4*j+3];
      A2 += w0*Y2[4*j]+w1*Y2[4*j+1]+w2*Y2[4*j+2]+w3*Y2[4*j+3];
    }
    #pragma unroll
    for (int j = 0; j < 2; j++) {
      float w0=0,w1=0,w2=0,w3=0;
      #pragma unroll
      for (int l = 0; l < 8; l++) {
        const float4 f = *(const float4*)(row0 + l*80 + 8 + 4*j);
        const float el = g.enc[l];
        w0 += el*f.x; w1 += el*f.y; w2 += el*f.z; w3 += el*f.w;
      }
      A0 += w0*Y0[16+4*j]+w1*Y0[16+4*j+1]+w2*Y0[16+4*j+2]+w3*Y0[16+4*j+3];
      A1 += w0*Y1[16+4*j]+w1*Y1[16+4*j+1]+w2*Y1[16+4*j+2]+w3*Y1[16+4*j+3];
      A2 += w0*Y2[16+4*j]+w1*Y2[16+4*j+1]+w2*Y2[16+4*j+2]+w3*Y2[16+4*j+3];
    }
    // W-part: P212 (V)
    float W0=0,W1=0,W2=0;
    #pragma unroll
    for (int j = 0; j < 4; j++) {
      float w0=0,w1=0,w2=0,w3=0;
      #pragma unroll
      for (int l = 0; l < 8; l++) {
        const float4 f = *(const float4*)(row0 + l*80 + 32 + 4*j);
        const float el = g.enc[l];
        w0 += el*f.x; w1 += el*f.y; w2 += el*f.z; w3 += el*f.w;
      }
      W0 += w0*Y0[4*j]+w1*Y0[4*j+1]+w2*Y0[4*j+2]+w3*Y0[4*j+3];
      W1 += w0*Y1[4*j]+w1*Y1[4*j+1]+w2*Y1[4*j+2]+w3*Y1[4*j+3];
      W2 += w0*Y2[4*j]+w1*Y2[4*j+1]+w2*Y2[4*j+2]+w3*Y2[4*j+3];
    }
    const float q0p = A0 + (hh1*W2 - hh2*W1) + hh0*sd;
    const float q1p = A1 + (hh2*W0 - hh0*W2) + hh1*sd;
    const float q2p = A2 + (hh0*W1 - hh1*W0) + hh2*sd;

    // phase3: w = sum_l enc*P022[d,l,:], acc = w . X (streamed)
    float w[8] = {0,0,0,0,0,0,0,0};
    #pragma unroll
    for (int l = 0; l < 8; l++) {
      const float4 fa = ((const float4*)(row0 + l*80))[0];
      const float4 fb = ((const float4*)(row0 + l*80))[1];
      const float el = g.enc[l];
      w[0]+=el*fa.x; w[1]+=el*fa.y; w[2]+=el*fa.z; w[3]+=el*fa.w;
      w[4]+=el*fb.x; w[5]+=el*fb.y; w[6]+=el*fb.z; w[7]+=el*fb.w;
    }
    float acc[9] = {0,0,0,0,0,0,0,0,0};
    #pragma unroll
    for (int t = 0; t < 18; t++) {
      const float4 f = xd4[t];
      acc[(4*t+0)%9] += w[(4*t+0)/9]*f.x;
      acc[(4*t+1)%9] += w[(4*t+1)/9]*f.y;
      acc[(4*t+2)%9] += w[(4*t+2)/9]*f.z;
      acc[(4*t+3)%9] += w[(4*t+3)/9]*f.w;
    }
    atomicAdd(o + d*9 + 0, 0.1f*(acc[0] + hh0*q0p));
    atomicAdd(o + d*9 + 1, 0.1f*(acc[1] + hh0*q1p));
    atomicAdd(o + d*9 + 2, 0.1f*(acc[2] + hh0*q2p));
    atomicAdd(o + d*9 + 3, 0.1f*(acc[3] + hh1*q0p));
    atomicAdd(o + d*9 + 4, 0.1f*(acc[4] + hh1*q1p));
    atomicAdd(o + d*9 + 5, 0.1f*(acc[5] + hh1*q2p));
    atomicAdd(o + d*9 + 6, 0.1f*(acc[6] + hh2*q0p));
    atomicAdd(o + d*9 + 7, 0.1f*(acc[7] + hh2*q1p));
    atomicAdd(o + d*9 + 8, 0.1f*(acc[8] + hh2*q2p));
  }
}

extern "C" void kernel_launch(void* const* d_in, const int* in_sizes, int n_in,
                              void* d_out, int out_size, void* d_ws, size_t ws_size,
                              hipStream_t stream) {
  const float* r_ij = (const float*)d_in[0];
  const float* x_a  = (const float*)d_in[1];
  const float* x_v  = (const float*)d_in[2];
  const float* x_d  = (const float*)d_in[3];
  const float* P000 = (const float*)d_in[4];
  const float* P110 = (const float*)d_in[5];
  const float* P220 = (const float*)d_in[6];
  const float* P011 = (const float*)d_in[7];
  const float* P101 = (const float*)d_in[8];
  const float* P121 = (const float*)d_in[9];
  const float* P211 = (const float*)d_in[10];
  const float* P111 = (const float*)d_in[11];
  const float* P022 = (const float*)d_in[12];
  const float* P202 = (const float*)d_in[13];
  const float* P112 = (const float*)d_in[14];
  const float* P222 = (const float*)d_in[15];
  const float* P212 = (const float*)d_in[16];
  const int* src = (const int*)d_in[17];
  const int* dst = (const int*)d_in[18];

  const int E = in_sizes[17];
  const int N = in_sizes[1] / 32;
  float* out = (float*)d_out;
  float* outA = out;
  float* outV = out + (size_t)N*32;
  float* outD = out + (size_t)N*80;

  hipMemsetAsync(d_out, 0, (size_t)out_size * sizeof(float), stream);

  const size_t need = 256 + (size_t)E * sizeof(int);
  int* cnt = nullptr;
  int* list = nullptr;
  if (ws_size >= need) {
    cnt  = (int*)d_ws;
    list = (int*)((char*)d_ws + 256);
    hipMemsetAsync(d_ws, 0, 256, stream);
    compact_k<<<(E + 255)/256, 256, 0, stream>>>(r_ij, E, cnt, list);
  }

  msgA_k<<<(E + 511)/512, 256, 0, stream>>>(r_ij, x_a, x_v, x_d,
      P000, P110, P220, src, dst, cnt, list, E, outA);
  msgV_k<<<(E + 255)/256, 256, 0, stream>>>(r_ij, x_a, x_v, x_d,
      P011, P101, P121, P211, P111, src, dst, cnt, list, E, outV);
  msgD_k<<<(E + 255)/256, 256, 0, stream>>>(r_ij, x_a, x_v, x_d,
      P022, P202, P112, P222, P212, src, dst, cnt, list, E, outD);
}

// Round 6
// 693.716 us; speedup vs baseline: 3.7309x; 3.7309x over previous
//
#include <hip/hip_runtime.h>

#define PI_F 3.14159265358979323846f

typedef _Float16 h8 __attribute__((ext_vector_type(8)));
typedef _Float16 h2v __attribute__((ext_vector_type(2)));
typedef float f4 __attribute__((ext_vector_type(4)));
typedef unsigned int u32;

struct Geom { float enc[8]; float h0, h1, h2; };

__device__ __forceinline__ bool geom_of(const float* __restrict__ r, int e, Geom& g) {
  const float rx = r[3*e], ry = r[3*e+1], rz = r[3*e+2];
  const float xsq = (rx*rx + ry*ry + rz*rz) * (1.0f/2.5f);
  const float cut = 1.0f - xsq;
  if (cut <= 0.0f) return false;
  const float c1 = cosf(PI_F * sqrtf(xsq));
  g.enc[0] = cut; g.enc[1] = c1*cut;
  float cp = 1.0f, cc = c1;
  #pragma unroll
  for (int n = 2; n < 8; n++) { float cn = 2.0f*c1*cc - cp; cp = cc; cc = cn; g.enc[n] = cn*cut; }
  const float s = 7.0f/2.5f;
  const float yx = rx*s, yy = ry*s, yz = rz*s;
  const float inv = rsqrtf(1.0f + yx*yx + yy*yy + yz*yz);
  g.h0 = yx*inv; g.h1 = yy*inv; g.h2 = yz*inv;
  return true;
}

__device__ __forceinline__ u32 pk2(float a, float b) {
  union { h2v h; u32 u; } r;
  r.h.x = (_Float16)a; r.h.y = (_Float16)b;
  return r.u;
}

__device__ __forceinline__ h8 mul_enc(uint4 c, u32 e) {
  union { uint4 u; h2v p[4]; } C; C.u = c;
  union { u32 u; h2v h; } E; E.u = e;
  union { h2v p[4]; h8 v; } R;
  #pragma unroll
  for (int i = 0; i < 4; i++) R.p[i] = C.p[i] * E.h;
  return R.v;
}

__device__ __forceinline__ h8 as_h8(uint4 c) { union { uint4 u; h8 v; } r; r.u = c; return r.v; }

__global__ __launch_bounds__(256) void compact_k(const float* __restrict__ r, int E,
                                                 int* __restrict__ cnt, int* __restrict__ list) {
  int e = blockIdx.x * 256 + threadIdx.x;
  if (e >= E) return;
  float rx = r[3*e], ry = r[3*e+1], rz = r[3*e+2];
  float xsq = (rx*rx + ry*ry + rz*rz) * (1.0f/2.5f);
  if (xsq < 1.0f) {
    int p = atomicAdd(cnt, 1);
    list[p] = e;
  }
}

// ============================ S kernel: psi_a ============================
// GEMM [16 edges x 448] * [448 x 32] per wave; features enc (x) [xa|s1|s2] fp16
__global__ __launch_bounds__(256, 3) void msgS_k(
    const float* __restrict__ r_ij, const float* __restrict__ x_a,
    const float* __restrict__ x_v,  const float* __restrict__ x_d,
    const float* __restrict__ P000, const float* __restrict__ P110, const float* __restrict__ P220,
    const int* __restrict__ src, const int* __restrict__ dst,
    const int* __restrict__ cnt, const int* __restrict__ list, int E,
    float* __restrict__ outA)
{
  const int nAct = list ? *cnt : E;
  if ((int)blockIdx.x * 64 >= nAct) return;

  __shared__ __align__(16) u32 sB[7168];        // 2 tiles x 14 steps x 64 lanes x 4
  __shared__ __align__(16) u32 sc[4][448];      // [wave][16 edges x 28 pk]
  __shared__ u32 senc[4][144];                  // [wave][16 x 9]
  __shared__ int sni[4][16];

  // ---- weight fragments: Ws[k=l*56+b][n=a]
  for (int i = threadIdx.x; i < 7168; i += 256) {
    const int p = i & 3, ln = (i >> 2) & 63, rest = i >> 8;
    const int step = rest % 14, tile = rest / 14;
    const int k = step*32 + (ln >> 4)*8 + 2*p;
    const int n = tile*16 + (ln & 15);
    const int l = k / 56, b = k - l*56;
    const int base = n*8 + l;
    float w0, w1;
    if (b < 32)      { w0 = P000[base*32 + b];      w1 = P000[base*32 + b + 1]; }
    else if (b < 48) { w0 = P110[base*16 + (b-32)]; w1 = P110[base*16 + (b-31)]; }
    else             { w0 = P220[base*8  + (b-48)]; w1 = P220[base*8  + (b-47)]; }
    sB[i] = pk2(w0, w1);
  }

  const int wv = threadIdx.x >> 6;
  const int lane = threadIdx.x & 63;
  // ---- per-edge features (4 lanes per edge)
  {
    const int et = lane >> 2, part = lane & 3;
    const int idx = blockIdx.x*64 + wv*16 + et;
    const int e = (idx < nAct) ? (list ? list[idx] : idx) : -1;
    Geom g;
    const bool ok = (e >= 0) && geom_of(r_ij, e, g);
    const int nj = ok ? dst[e] : 0;
    if (part <= 1) {
      if (ok) {
        const float4* xa4 = (const float4*)(x_a + (size_t)nj*32);
        #pragma unroll
        for (int q = 0; q < 4; q++) {
          float4 f = xa4[part*4 + q];
          sc[wv][et*28 + part*8 + 2*q]     = pk2(f.x, f.y);
          sc[wv][et*28 + part*8 + 2*q + 1] = pk2(f.z, f.w);
        }
      } else {
        #pragma unroll
        for (int q = 0; q < 8; q++) sc[wv][et*28 + part*8 + q] = 0;
      }
    } else if (part == 2) {
      if (ok) {
        float vb[48];
        const float4* xv4 = (const float4*)(x_v + (size_t)nj*48);
        #pragma unroll
        for (int q = 0; q < 12; q++) { float4 f = xv4[q]; vb[4*q]=f.x; vb[4*q+1]=f.y; vb[4*q+2]=f.z; vb[4*q+3]=f.w; }
        #pragma unroll
        for (int t = 0; t < 8; t++) {
          float a = g.h0*vb[6*t+0] + g.h1*vb[6*t+1] + g.h2*vb[6*t+2];
          float b = g.h0*vb[6*t+3] + g.h1*vb[6*t+4] + g.h2*vb[6*t+5];
          sc[wv][et*28 + 16 + t] = pk2(a, b);
        }
      } else {
        #pragma unroll
        for (int t = 0; t < 8; t++) sc[wv][et*28 + 16 + t] = 0;
      }
    } else {
      if (ok) {
        float db[72];
        const float4* xd4 = (const float4*)(x_d + (size_t)nj*72);
        #pragma unroll
        for (int q = 0; q < 18; q++) { float4 f = xd4[q]; db[4*q]=f.x; db[4*q+1]=f.y; db[4*q+2]=f.z; db[4*q+3]=f.w; }
        #pragma unroll
        for (int t = 0; t < 4; t++) {
          const float* m0 = db + 9*(2*t);
          const float* m1 = db + 9*(2*t+1);
          float a = g.h0*(g.h0*m0[0]+g.h1*m0[3]+g.h2*m0[6]) + g.h1*(g.h0*m0[1]+g.h1*m0[4]+g.h2*m0[7]) + g.h2*(g.h0*m0[2]+g.h1*m0[5]+g.h2*m0[8]);
          float b = g.h0*(g.h0*m1[0]+g.h1*m1[3]+g.h2*m1[6]) + g.h1*(g.h0*m1[1]+g.h1*m1[4]+g.h2*m1[7]) + g.h2*(g.h0*m1[2]+g.h1*m1[5]+g.h2*m1[8]);
          sc[wv][et*28 + 24 + t] = pk2(a, b);
        }
        #pragma unroll
        for (int l = 0; l < 8; l++) senc[wv][et*9 + l] = pk2(g.enc[l], g.enc[l]);
        sni[wv][et] = src[e];
      } else {
        #pragma unroll
        for (int t = 0; t < 4; t++) sc[wv][et*28 + 24 + t] = 0;
        #pragma unroll
        for (int l = 0; l < 8; l++) senc[wv][et*9 + l] = 0;
        sni[wv][et] = -1;
      }
    }
  }
  __syncthreads();
  if (blockIdx.x*64 + wv*16 >= nAct) return;

  const int row = lane & 15, kg = lane >> 4;
  const u32* scw = sc[wv];
  const u32* sew = senc[wv];
  f4 acc0 = {0,0,0,0}, acc1 = {0,0,0,0};
  #pragma unroll
  for (int s = 0; s < 14; s++) {
    const int m = 4*s + kg;
    const int l = m / 7;
    const int j = m - l*7;
    const uint4 ca = *(const uint4*)&scw[row*28 + j*4];
    const h8 af = mul_enc(ca, sew[row*9 + l]);
    const h8 b0 = as_h8(*(const uint4*)&sB[(s*64 + lane)*4]);
    const h8 b1 = as_h8(*(const uint4*)&sB[((14 + s)*64 + lane)*4]);
    acc0 = __builtin_amdgcn_mfma_f32_16x16x32_f16(af, b0, acc0, 0, 0, 0);
    acc1 = __builtin_amdgcn_mfma_f32_16x16x32_f16(af, b1, acc1, 0, 0, 0);
  }
  const int col = lane & 15;
  #pragma unroll
  for (int i = 0; i < 4; i++) {
    const int ni = sni[wv][kg*4 + i];
    if (ni < 0) continue;
    float* o = outA + (size_t)ni*32 + col;
    atomicAdd(o,      0.1f*acc0[i]);
    atomicAdd(o + 16, 0.1f*acc1[i]);
  }
}

// ============================ V kernel: psi_v ============================
__global__ __launch_bounds__(256, 3) void msgV_k(
    const float* __restrict__ r_ij, const float* __restrict__ x_a,
    const float* __restrict__ x_v,  const float* __restrict__ x_d,
    const float* __restrict__ P011, const float* __restrict__ P101, const float* __restrict__ P121,
    const float* __restrict__ P211, const float* __restrict__ P111,
    const int* __restrict__ src, const int* __restrict__ dst,
    const int* __restrict__ cnt, const int* __restrict__ list, int E,
    float* __restrict__ outV)
{
  const int nAct = list ? *cnt : E;
  if ((int)blockIdx.x * 64 >= nAct) return;

  __shared__ __align__(16) u32 sB[6144];        // [0,3072): scv 12 steps; [3072,6144): Y 2 tiles x 6 steps
  __shared__ __align__(16) u32 sxs[4][448];     // [16 x 28] : xa(16pk) | s1(8pk)
  __shared__ __align__(16) u32 sY[4][704];      // [16 x 44] : 3 comps x (V 8pk | T 4pk)
  __shared__ u32 senc[4][144];
  __shared__ float sh[4][48];
  __shared__ int sni[4][16];

  for (int i = threadIdx.x; i < 6144; i += 256) {
    const int p = i & 3, ln = (i >> 2) & 63;
    const int n = ln & 15, kgq = ln >> 4;
    float w0 = 0.0f, w1 = 0.0f;
    if (i < 3072) {                     // scv: Ws[k=l*48+ch][v]
      const int step = i >> 8;
      const int k = step*32 + kgq*8 + 2*p;
      const int l = k / 48, ch = k - l*48;
      const int base = n*8 + l;
      if (ch < 32) { w0 = P101[base*32 + ch];      w1 = P101[base*32 + ch + 1]; }
      else         { w0 = P211[base*16 + (ch-32)]; w1 = P211[base*16 + (ch-31)]; }
    } else {                            // Y: Ws[k=l*24+ch][v], tiles A / W
      const int iy = i - 3072;
      const int rest = iy >> 8;
      const int step = rest % 6, tile = rest / 6;
      const int k = step*32 + kgq*8 + 2*p;
      const int l = k / 24, ch = k - l*24;
      const int base = n*8 + l;
      if (tile == 0) {
        if (ch < 16) { w0 = P011[base*16 + ch];      w1 = P011[base*16 + ch + 1]; }
        else         { w0 = P121[base*8 + (ch-16)];  w1 = P121[base*8 + (ch-15)]; }
      } else {
        if (ch < 16) { w0 = P111[base*16 + ch];      w1 = P111[base*16 + ch + 1]; }
      }
    }
    sB[i] = pk2(w0, w1);
  }

  const int wv = threadIdx.x >> 6;
  const int lane = threadIdx.x & 63;
  {
    const int et = lane >> 2, part = lane & 3;
    const int idx = blockIdx.x*64 + wv*16 + et;
    const int e = (idx < nAct) ? (list ? list[idx] : idx) : -1;
    Geom g;
    const bool ok = (e >= 0) && geom_of(r_ij, e, g);
    const int nj = ok ? dst[e] : 0;
    if (part == 0) {
      if (ok) {
        const float4* xa4 = (const float4*)(x_a + (size_t)nj*32);
        #pragma unroll
        for (int q = 0; q < 8; q++) {
          float4 f = xa4[q];
          sxs[wv][et*28 + 2*q]     = pk2(f.x, f.y);
          sxs[wv][et*28 + 2*q + 1] = pk2(f.z, f.w);
        }
      } else {
        #pragma unroll
        for (int q = 0; q < 16; q++) sxs[wv][et*28 + q] = 0;
      }
    } else if (part == 1) {
      if (ok) {
        float vb[48];
        const float4* xv4 = (const float4*)(x_v + (size_t)nj*48);
        #pragma unroll
        for (int q = 0; q < 12; q++) { float4 f = xv4[q]; vb[4*q]=f.x; vb[4*q+1]=f.y; vb[4*q+2]=f.z; vb[4*q+3]=f.w; }
        #pragma unroll
        for (int c = 0; c < 3; c++)
          #pragma unroll
          for (int t = 0; t < 8; t++)
            sY[wv][et*44 + c*12 + t] = pk2(vb[6*t + c], vb[6*t + 3 + c]);
        #pragma unroll
        for (int t = 0; t < 8; t++) {
          float a = g.h0*vb[6*t+0] + g.h1*vb[6*t+1] + g.h2*vb[6*t+2];
          float b = g.h0*vb[6*t+3] + g.h1*vb[6*t+4] + g.h2*vb[6*t+5];
          sxs[wv][et*28 + 16 + t] = pk2(a, b);
        }
      } else {
        #pragma unroll
        for (int c = 0; c < 3; c++)
          #pragma unroll
          for (int t = 0; t < 8; t++) sY[wv][et*44 + c*12 + t] = 0;
        #pragma unroll
        for (int t = 0; t < 8; t++) sxs[wv][et*28 + 16 + t] = 0;
      }
    } else if (part == 2) {
      if (ok) {
        float db[72];
        const float4* xd4 = (const float4*)(x_d + (size_t)nj*72);
        #pragma unroll
        for (int q = 0; q < 18; q++) { float4 f = xd4[q]; db[4*q]=f.x; db[4*q+1]=f.y; db[4*q+2]=f.z; db[4*q+3]=f.w; }
        #pragma unroll
        for (int c = 0; c < 3; c++)
          #pragma unroll
          for (int t = 0; t < 4; t++) {
            float a = g.h0*db[9*(2*t)+c]   + g.h1*db[9*(2*t)+3+c]   + g.h2*db[9*(2*t)+6+c];
            float b = g.h0*db[9*(2*t+1)+c] + g.h1*db[9*(2*t+1)+3+c] + g.h2*db[9*(2*t+1)+6+c];
            sY[wv][et*44 + c*12 + 8 + t] = pk2(a, b);
          }
      } else {
        #pragma unroll
        for (int c = 0; c < 3; c++)
          #pragma unroll
          for (int t = 0; t < 4; t++) sY[wv][et*44 + c*12 + 8 + t] = 0;
      }
    } else {
      if (ok) {
        #pragma unroll
        for (int l = 0; l < 8; l++) senc[wv][et*9 + l] = pk2(g.enc[l], g.enc[l]);
        sh[wv][et*3+0] = g.h0; sh[wv][et*3+1] = g.h1; sh[wv][et*3+2] = g.h2;
        sni[wv][et] = src[e];
      } else {
        #pragma unroll
        for (int l = 0; l < 8; l++) senc[wv][et*9 + l] = 0;
        sh[wv][et*3+0] = 0; sh[wv][et*3+1] = 0; sh[wv][et*3+2] = 0;
        sni[wv][et] = -1;
      }
    }
  }
  __syncthreads();
  if (blockIdx.x*64 + wv*16 >= nAct) return;

  const int row = lane & 15, kg = lane >> 4;
  const u32* sxw = sxs[wv];
  const u32* syw = sY[wv];
  const u32* sew = senc[wv];

  f4 accS = {0,0,0,0};
  #pragma unroll
  for (int s = 0; s < 12; s++) {
    const int m = 4*s + kg;
    const int l = m / 6;
    const int j = m - l*6;
    const uint4 ca = *(const uint4*)&sxw[row*28 + j*4];
    const h8 af = mul_enc(ca, sew[row*9 + l]);
    const h8 bf = as_h8(*(const uint4*)&sB[(s*64 + lane)*4]);
    accS = __builtin_amdgcn_mfma_f32_16x16x32_f16(af, bf, accS, 0, 0, 0);
  }

  f4 accA[3], accW[3];
  #pragma unroll
  for (int c = 0; c < 3; c++) { accA[c] = f4{0,0,0,0}; accW[c] = f4{0,0,0,0}; }
  #pragma unroll
  for (int c = 0; c < 3; c++) {
    #pragma unroll
    for (int s = 0; s < 6; s++) {
      const int m = 4*s + kg;
      const int l = m / 3;
      const int j = m - l*3;
      const uint4 ca = *(const uint4*)&syw[row*44 + c*12 + j*4];
      const h8 af = mul_enc(ca, sew[row*9 + l]);
      const h8 bA = as_h8(*(const uint4*)&sB[3072 + (s*64 + lane)*4]);
      const h8 bW = as_h8(*(const uint4*)&sB[3072 + ((6 + s)*64 + lane)*4]);
      accA[c] = __builtin_amdgcn_mfma_f32_16x16x32_f16(af, bA, accA[c], 0, 0, 0);
      accW[c] = __builtin_amdgcn_mfma_f32_16x16x32_f16(af, bW, accW[c], 0, 0, 0);
    }
  }

  const int v = lane & 15;
  #pragma unroll
  for (int i = 0; i < 4; i++) {
    const int r = kg*4 + i;
    const int ni = sni[wv][r];
    if (ni < 0) continue;
    const float h0 = sh[wv][r*3], h1 = sh[wv][r*3+1], h2 = sh[wv][r*3+2];
    const float sv = accS[i];
    const float A0 = accA[0][i], A1 = accA[1][i], A2 = accA[2][i];
    const float W0 = accW[0][i], W1 = accW[1][i], W2 = accW[2][i];
    float* o = outV + (size_t)ni*48 + v*3;
    atomicAdd(o + 0, 0.1f*(A0 + (h1*W2 - h2*W1) + h0*sv));
    atomicAdd(o + 1, 0.1f*(A1 + (h2*W0 - h0*W2) + h1*sv));
    atomicAdd(o + 2, 0.1f*(A2 + (h0*W1 - h1*W0) + h2*sv));
  }
}

// ============================ D kernel: psi_d ============================
__global__ __launch_bounds__(256, 3) void msgD_k(
    const float* __restrict__ r_ij, const float* __restrict__ x_a,
    const float* __restrict__ x_v,  const float* __restrict__ x_d,
    const float* __restrict__ P022, const float* __restrict__ P202, const float* __restrict__ P112,
    const float* __restrict__ P222, const float* __restrict__ P212,
    const int* __restrict__ src, const int* __restrict__ dst,
    const int* __restrict__ cnt, const int* __restrict__ list, int E,
    float* __restrict__ outD)
{
  const int nAct = list ? *cnt : E;
  if ((int)blockIdx.x * 64 >= nAct) return;

  __shared__ __align__(16) u32 sB[4096];        // [0,2048): scd 8 steps; [2048,3584): Y packed A|W 6 steps; [3584,4096): X 2 steps
  __shared__ __align__(16) u32 sxa[4][320];     // [16 x 20]: xa 16pk
  __shared__ __align__(16) u32 sY[4][704];      // [16 x 44]
  __shared__ __align__(16) u32 sX[4][704];      // [16 x 44]: 9 ij x 4pk
  __shared__ u32 senc[4][144];
  __shared__ float sh[4][48];
  __shared__ int sni[4][16];

  for (int i = threadIdx.x; i < 4096; i += 256) {
    const int p = i & 3, ln = (i >> 2) & 63;
    const int n16 = ln & 15, kgq = ln >> 4;
    float w0 = 0.0f, w1 = 0.0f;
    if (i < 2048) {                      // scd: k = l*32 + ch
      const int step = i >> 8;
      const int k = step*32 + kgq*8 + 2*p;
      const int l = k >> 5, ch = k & 31;
      if (n16 < 8) { const int b = (n16*8 + l)*32 + ch; w0 = P202[b]; w1 = P202[b+1]; }
    } else if (i < 3584) {               // Y packed: cols 0-7 = A (P112/P222), 8-15 = W (P212)
      const int step = (i - 2048) >> 8;
      const int k = step*32 + kgq*8 + 2*p;
      const int l = k / 24, ch = k - l*24;
      if (n16 < 8) {
        if (ch < 16) { const int b = (n16*8 + l)*16 + ch;      w0 = P112[b]; w1 = P112[b+1]; }
        else         { const int b = (n16*8 + l)*8 + (ch-16);  w0 = P222[b]; w1 = P222[b+1]; }
      } else {
        const int d_ = n16 - 8;
        if (ch < 16) { const int b = (d_*8 + l)*16 + ch;       w0 = P212[b]; w1 = P212[b+1]; }
      }
    } else {                             // X: k = l*8 + b
      const int step = (i - 3584) >> 8;
      const int k = step*32 + kgq*8 + 2*p;
      const int l = k >> 3, bb = k & 7;
      if (n16 < 8) { const int b = (n16*8 + l)*8 + bb; w0 = P022[b]; w1 = P022[b+1]; }
    }
    sB[i] = pk2(w0, w1);
  }

  const int wv = threadIdx.x >> 6;
  const int lane = threadIdx.x & 63;
  {
    const int et = lane >> 2, part = lane & 3;
    const int idx = blockIdx.x*64 + wv*16 + et;
    const int e = (idx < nAct) ? (list ? list[idx] : idx) : -1;
    Geom g;
    const bool ok = (e >= 0) && geom_of(r_ij, e, g);
    const int nj = ok ? dst[e] : 0;
    if (part == 0) {
      if (ok) {
        const float4* xa4 = (const float4*)(x_a + (size_t)nj*32);
        #pragma unroll
        for (int q = 0; q < 8; q++) {
          float4 f = xa4[q];
          sxa[wv][et*20 + 2*q]     = pk2(f.x, f.y);
          sxa[wv][et*20 + 2*q + 1] = pk2(f.z, f.w);
        }
        #pragma unroll
        for (int l = 0; l < 8; l++) senc[wv][et*9 + l] = pk2(g.enc[l], g.enc[l]);
        sh[wv][et*3+0] = g.h0; sh[wv][et*3+1] = g.h1; sh[wv][et*3+2] = g.h2;
        sni[wv][et] = src[e];
      } else {
        #pragma unroll
        for (int q = 0; q < 16; q++) sxa[wv][et*20 + q] = 0;
        #pragma unroll
        for (int l = 0; l < 8; l++) senc[wv][et*9 + l] = 0;
        sh[wv][et*3+0] = 0; sh[wv][et*3+1] = 0; sh[wv][et*3+2] = 0;
        sni[wv][et] = -1;
      }
    } else if (part == 1) {
      if (ok) {
        float vb[48];
        const float4* xv4 = (const float4*)(x_v + (size_t)nj*48);
        #pragma unroll
        for (int q = 0; q < 12; q++) { float4 f = xv4[q]; vb[4*q]=f.x; vb[4*q+1]=f.y; vb[4*q+2]=f.z; vb[4*q+3]=f.w; }
        #pragma unroll
        for (int c = 0; c < 3; c++)
          #pragma unroll
          for (int t = 0; t < 8; t++)
            sY[wv][et*44 + c*12 + t] = pk2(vb[6*t + c], vb[6*t + 3 + c]);
      } else {
        #pragma unroll
        for (int c = 0; c < 3; c++)
          #pragma unroll
          for (int t = 0; t < 8; t++) sY[wv][et*44 + c*12 + t] = 0;
      }
    } else if (part == 2) {
      if (ok) {
        float db[72];
        const float4* xd4 = (const float4*)(x_d + (size_t)nj*72);
        #pragma unroll
        for (int q = 0; q < 18; q++) { float4 f = xd4[q]; db[4*q]=f.x; db[4*q+1]=f.y; db[4*q+2]=f.z; db[4*q+3]=f.w; }
        #pragma unroll
        for (int c = 0; c < 3; c++)
          #pragma unroll
          for (int t = 0; t < 4; t++) {
            float a = g.h0*db[9*(2*t)+c]   + g.h1*db[9*(2*t)+3+c]   + g.h2*db[9*(2*t)+6+c];
            float b = g.h0*db[9*(2*t+1)+c] + g.h1*db[9*(2*t+1)+3+c] + g.h2*db[9*(2*t+1)+6+c];
            sY[wv][et*44 + c*12 + 8 + t] = pk2(a, b);
          }
      } else {
        #pragma unroll
        for (int c = 0; c < 3; c++)
          #pragma unroll
          for (int t = 0; t < 4; t++) sY[wv][et*44 + c*12 + 8 + t] = 0;
      }
    } else {
      if (ok) {
        float db[72];
        const float4* xd4 = (const float4*)(x_d + (size_t)nj*72);
        #pragma unroll
        for (int q = 0; q < 18; q++) { float4 f = xd4[q]; db[4*q]=f.x; db[4*q+1]=f.y; db[4*q+2]=f.z; db[4*q+3]=f.w; }
        #pragma unroll
        for (int ij = 0; ij < 9; ij++)
          #pragma unroll
          for (int pp = 0; pp < 4; pp++)
            sX[wv][et*44 + ij*4 + pp] = pk2(db[(2*pp)*9 + ij], db[(2*pp+1)*9 + ij]);
      } else {
        #pragma unroll
        for (int q = 0; q < 36; q++) sX[wv][et*44 + q] = 0;
      }
    }
  }
  __syncthreads();
  if (blockIdx.x*64 + wv*16 >= nAct) return;

  const int row = lane & 15, kg = lane >> 4;
  const u32* saw = sxa[wv];
  const u32* syw = sY[wv];
  const u32* sxw = sX[wv];
  const u32* sew = senc[wv];

  // scd (cols 0-7)
  f4 accSd = {0,0,0,0};
  #pragma unroll
  for (int s = 0; s < 8; s++) {
    const int m = 4*s + kg;
    const int l = m >> 2, j = m & 3;
    const uint4 ca = *(const uint4*)&saw[row*20 + j*4];
    const h8 af = mul_enc(ca, sew[row*9 + l]);
    const h8 bf = as_h8(*(const uint4*)&sB[(s*64 + lane)*4]);
    accSd = __builtin_amdgcn_mfma_f32_16x16x32_f16(af, bf, accSd, 0, 0, 0);
  }

  // Y packed A|W per component
  f4 accY[3];
  #pragma unroll
  for (int c = 0; c < 3; c++) accY[c] = f4{0,0,0,0};
  #pragma unroll
  for (int c = 0; c < 3; c++) {
    #pragma unroll
    for (int s = 0; s < 6; s++) {
      const int m = 4*s + kg;
      const int l = m / 3;
      const int j = m - l*3;
      const uint4 ca = *(const uint4*)&syw[row*44 + c*12 + j*4];
      const h8 af = mul_enc(ca, sew[row*9 + l]);
      const h8 bf = as_h8(*(const uint4*)&sB[2048 + (s*64 + lane)*4]);
      accY[c] = __builtin_amdgcn_mfma_f32_16x16x32_f16(af, bf, accY[c], 0, 0, 0);
    }
  }

  // Q[i][j] = A_j + (h x W)_j + h_j*scd   (valid on cols 0-7)
  float Q[12];
  #pragma unroll
  for (int i = 0; i < 4; i++) {
    const int r = kg*4 + i;
    const float h0 = sh[wv][r*3], h1 = sh[wv][r*3+1], h2 = sh[wv][r*3+2];
    const float sd = accSd[i];
    const float A0 = accY[0][i], A1 = accY[1][i], A2 = accY[2][i];
    const float W0 = __shfl_xor(A0, 8, 64);
    const float W1 = __shfl_xor(A1, 8, 64);
    const float W2 = __shfl_xor(A2, 8, 64);
    Q[i*3+0] = A0 + (h1*W2 - h2*W1) + h0*sd;
    Q[i*3+1] = A1 + (h2*W0 - h0*W2) + h1*sd;
    Q[i*3+2] = A2 + (h0*W1 - h1*W0) + h2*sd;
  }

  // X part: 9 ij tiles
  f4 accX[9];
  #pragma unroll
  for (int ij = 0; ij < 9; ij++) accX[ij] = f4{0,0,0,0};
  #pragma unroll
  for (int ij = 0; ij < 9; ij++) {
    const uint4 ca = *(const uint4*)&sxw[row*44 + ij*4];
    #pragma unroll
    for (int s = 0; s < 2; s++) {
      const h8 af = mul_enc(ca, sew[row*9 + 4*s + kg]);
      const h8 bf = as_h8(*(const uint4*)&sB[3584 + (s*64 + lane)*4]);
      accX[ij] = __builtin_amdgcn_mfma_f32_16x16x32_f16(af, bf, accX[ij], 0, 0, 0);
    }
  }

  const int d = lane & 15;
  if (d < 8) {
    #pragma unroll
    for (int i = 0; i < 4; i++) {
      const int r = kg*4 + i;
      const int ni = sni[wv][r];
      if (ni < 0) continue;
      const float hh[3] = { sh[wv][r*3], sh[wv][r*3+1], sh[wv][r*3+2] };
      float* o = outD + (size_t)ni*72 + d*9;
      #pragma unroll
      for (int ii = 0; ii < 3; ii++)
        #pragma unroll
        for (int jj = 0; jj < 3; jj++)
          atomicAdd(o + ii*3 + jj, 0.1f*(accX[ii*3+jj][i] + hh[ii]*Q[i*3+jj]));
    }
  }
}

extern "C" void kernel_launch(void* const* d_in, const int* in_sizes, int n_in,
                              void* d_out, int out_size, void* d_ws, size_t ws_size,
                              hipStream_t stream) {
  const float* r_ij = (const float*)d_in[0];
  const float* x_a  = (const float*)d_in[1];
  const float* x_v  = (const float*)d_in[2];
  const float* x_d  = (const float*)d_in[3];
  const float* P000 = (const float*)d_in[4];
  const float* P110 = (const float*)d_in[5];
  const float* P220 = (const float*)d_in[6];
  const float* P011 = (const float*)d_in[7];
  const float* P101 = (const float*)d_in[8];
  const float* P121 = (const float*)d_in[9];
  const float* P211 = (const float*)d_in[10];
  const float* P111 = (const float*)d_in[11];
  const float* P022 = (const float*)d_in[12];
  const float* P202 = (const float*)d_in[13];
  const float* P112 = (const float*)d_in[14];
  const float* P222 = (const float*)d_in[15];
  const float* P212 = (const float*)d_in[16];
  const int* src = (const int*)d_in[17];
  const int* dst = (const int*)d_in[18];

  const int E = in_sizes[17];
  const int N = in_sizes[1] / 32;
  float* out = (float*)d_out;
  float* outA = out;
  float* outV = out + (size_t)N*32;
  float* outD = out + (size_t)N*80;

  hipMemsetAsync(d_out, 0, (size_t)out_size * sizeof(float), stream);

  const size_t need = 256 + (size_t)E * sizeof(int);
  int* cnt = nullptr;
  int* list = nullptr;
  if (ws_size >= need) {
    cnt  = (int*)d_ws;
    list = (int*)((char*)d_ws + 256);
    hipMemsetAsync(d_ws, 0, 256, stream);
    compact_k<<<(E + 255)/256, 256, 0, stream>>>(r_ij, E, cnt, list);
  }

  const int nb = (E + 63) / 64;
  msgS_k<<<nb, 256, 0, stream>>>(r_ij, x_a, x_v, x_d,
      P000, P110, P220, src, dst, cnt, list, E, outA);
  msgV_k<<<nb, 256, 0, stream>>>(r_ij, x_a, x_v, x_d,
      P011, P101, P121, P211, P111, src, dst, cnt, list, E, outV);
  msgD_k<<<nb, 256, 0, stream>>>(r_ij, x_a, x_v, x_d,
      P022, P202, P112, P222, P212, src, dst, cnt, list, E, outD);
}

// Round 8
// 473.226 us; speedup vs baseline: 5.4692x; 1.4659x over previous
//
#include <hip/hip_runtime.h>

#define PI_F 3.14159265358979323846f

typedef _Float16 h8 __attribute__((ext_vector_type(8)));
typedef _Float16 h2v __attribute__((ext_vector_type(2)));
typedef float f4 __attribute__((ext_vector_type(4)));
typedef unsigned int u32;

struct Geom { float enc[8]; float h0, h1, h2; };

__device__ __forceinline__ bool geom_of(const float* __restrict__ r, int e, Geom& g) {
  const float rx = r[3*e], ry = r[3*e+1], rz = r[3*e+2];
  const float xsq = (rx*rx + ry*ry + rz*rz) * (1.0f/2.5f);
  const float cut = 1.0f - xsq;
  if (cut <= 0.0f) return false;
  const float c1 = cosf(PI_F * sqrtf(xsq));
  g.enc[0] = cut; g.enc[1] = c1*cut;
  float cp = 1.0f, cc = c1;
  #pragma unroll
  for (int n = 2; n < 8; n++) { float cn = 2.0f*c1*cc - cp; cp = cc; cc = cn; g.enc[n] = cn*cut; }
  const float s = 7.0f/2.5f;
  const float yx = rx*s, yy = ry*s, yz = rz*s;
  const float inv = rsqrtf(1.0f + yx*yx + yy*yy + yz*yz);
  g.h0 = yx*inv; g.h1 = yy*inv; g.h2 = yz*inv;
  return true;
}

__device__ __forceinline__ u32 pk2(float a, float b) {
  union { h2v h; u32 u; } r;
  r.h.x = (_Float16)a; r.h.y = (_Float16)b;
  return r.u;
}

__device__ __forceinline__ h8 mul_enc(uint4 c, u32 e) {
  union { uint4 u; h2v p[4]; } C; C.u = c;
  union { u32 u; h2v h; } E; E.u = e;
  union { h2v p[4]; h8 v; } R;
  #pragma unroll
  for (int i = 0; i < 4; i++) R.p[i] = C.p[i] * E.h;
  return R.v;
}

__device__ __forceinline__ h8 as_h8(uint4 c) { union { uint4 u; h8 v; } r; r.u = c; return r.v; }

// ======================= CSR build =======================
__global__ __launch_bounds__(256) void hist_k(const float* __restrict__ r, const int* __restrict__ src,
                                              int E, int* __restrict__ hist) {
  int e = blockIdx.x * 256 + threadIdx.x;
  if (e >= E) return;
  float rx = r[3*e], ry = r[3*e+1], rz = r[3*e+2];
  float xsq = (rx*rx + ry*ry + rz*rz) * (1.0f/2.5f);
  if (xsq < 1.0f) atomicAdd(&hist[src[e]], 1);
}

__global__ __launch_bounds__(256) void scan_k(int* __restrict__ hist, int Nn, int* __restrict__ row_ptr) {
  __shared__ int part[256];
  const int t = threadIdx.x;
  const int chunk = (Nn + 255) / 256;
  const int i0 = t * chunk;
  int s = 0;
  for (int j = 0; j < chunk; j++) { int i = i0 + j; if (i < Nn) s += hist[i]; }
  part[t] = s;
  __syncthreads();
  for (int off = 1; off < 256; off <<= 1) {
    int v = (t >= off) ? part[t - off] : 0;
    __syncthreads();
    part[t] += v;
    __syncthreads();
  }
  int run = part[t] - s;   // exclusive prefix of this thread's chunk
  for (int j = 0; j < chunk; j++) {
    int i = i0 + j;
    if (i < Nn) { int h = hist[i]; row_ptr[i] = run; hist[i] = run; run += h; }  // hist becomes cursor
  }
  if (t == 255) row_ptr[Nn] = part[255];
}

__global__ __launch_bounds__(256) void scatter_k(const float* __restrict__ r, const int* __restrict__ src,
                                                 int E, int* __restrict__ cur, int* __restrict__ sorted) {
  int e = blockIdx.x * 256 + threadIdx.x;
  if (e >= E) return;
  float rx = r[3*e], ry = r[3*e+1], rz = r[3*e+2];
  float xsq = (rx*rx + ry*ry + rz*rz) * (1.0f/2.5f);
  if (xsq < 1.0f) {
    int p = atomicAdd(&cur[src[e]], 1);
    sorted[p] = e;
  }
}

// ======================= CSR node-owner kernels =======================
// S: psi_a. wave = node; chunks of 16 edges; acc accumulates across chunks; shfl-reduce; plain store.
__global__ __launch_bounds__(256, 3) void msgS_csr(
    const float* __restrict__ r_ij, const float* __restrict__ x_a,
    const float* __restrict__ x_v,  const float* __restrict__ x_d,
    const float* __restrict__ P000, const float* __restrict__ P110, const float* __restrict__ P220,
    const int* __restrict__ dst,
    const int* __restrict__ row_ptr, const int* __restrict__ sorted, int Nn,
    float* __restrict__ outA)
{
  __shared__ __align__(16) u32 sB[7168];
  __shared__ __align__(16) u32 sc[4][448];
  __shared__ u32 senc[4][144];
  __shared__ int scnt[4];

  for (int i = threadIdx.x; i < 7168; i += 256) {
    const int p = i & 3, ln = (i >> 2) & 63, rest = i >> 8;
    const int step = rest % 14, tile = rest / 14;
    const int k = step*32 + (ln >> 4)*8 + 2*p;
    const int n = tile*16 + (ln & 15);
    const int l = k / 56, b = k - l*56;
    const int base = n*8 + l;
    float w0, w1;
    if (b < 32)      { w0 = P000[base*32 + b];      w1 = P000[base*32 + b + 1]; }
    else if (b < 48) { w0 = P110[base*16 + (b-32)]; w1 = P110[base*16 + (b-31)]; }
    else             { w0 = P220[base*8  + (b-48)]; w1 = P220[base*8  + (b-47)]; }
    sB[i] = pk2(w0, w1);
  }

  const int wv = threadIdx.x >> 6;
  const int lane = threadIdx.x & 63;
  const int n = blockIdx.x*4 + wv;
  int beg = 0, end = 0;
  if (n < Nn) { beg = row_ptr[n]; end = row_ptr[n+1]; }
  if (lane == 0) scnt[wv] = (end - beg + 15) >> 4;
  __syncthreads();
  const int umax = max(max(scnt[0],scnt[1]), max(scnt[2],scnt[3]));

  const int et = lane >> 2, part = lane & 3;
  const int row = lane & 15, kg = lane >> 4;
  f4 acc0 = {0,0,0,0}, acc1 = {0,0,0,0};

  for (int ch = 0; ch < umax; ch++) {
    {
      const int ei = beg + ch*16 + et;
      const int e = (ei < end) ? sorted[ei] : -1;
      Geom g;
      const bool ok = (e >= 0) && geom_of(r_ij, e, g);
      const int nj = ok ? dst[e] : 0;
      if (part <= 1) {
        if (ok) {
          const float4* xa4 = (const float4*)(x_a + (size_t)nj*32);
          #pragma unroll
          for (int q = 0; q < 4; q++) {
            float4 f = xa4[part*4 + q];
            sc[wv][et*28 + part*8 + 2*q]     = pk2(f.x, f.y);
            sc[wv][et*28 + part*8 + 2*q + 1] = pk2(f.z, f.w);
          }
        } else {
          #pragma unroll
          for (int q = 0; q < 8; q++) sc[wv][et*28 + part*8 + q] = 0;
        }
      } else if (part == 2) {
        if (ok) {
          float vb[48];
          const float4* xv4 = (const float4*)(x_v + (size_t)nj*48);
          #pragma unroll
          for (int q = 0; q < 12; q++) { float4 f = xv4[q]; vb[4*q]=f.x; vb[4*q+1]=f.y; vb[4*q+2]=f.z; vb[4*q+3]=f.w; }
          #pragma unroll
          for (int t = 0; t < 8; t++) {
            float a = g.h0*vb[6*t+0] + g.h1*vb[6*t+1] + g.h2*vb[6*t+2];
            float b = g.h0*vb[6*t+3] + g.h1*vb[6*t+4] + g.h2*vb[6*t+5];
            sc[wv][et*28 + 16 + t] = pk2(a, b);
          }
        } else {
          #pragma unroll
          for (int t = 0; t < 8; t++) sc[wv][et*28 + 16 + t] = 0;
        }
      } else {
        if (ok) {
          float db[72];
          const float4* xd4 = (const float4*)(x_d + (size_t)nj*72);
          #pragma unroll
          for (int q = 0; q < 18; q++) { float4 f = xd4[q]; db[4*q]=f.x; db[4*q+1]=f.y; db[4*q+2]=f.z; db[4*q+3]=f.w; }
          #pragma unroll
          for (int t = 0; t < 4; t++) {
            const float* m0 = db + 9*(2*t);
            const float* m1 = db + 9*(2*t+1);
            float a = g.h0*(g.h0*m0[0]+g.h1*m0[3]+g.h2*m0[6]) + g.h1*(g.h0*m0[1]+g.h1*m0[4]+g.h2*m0[7]) + g.h2*(g.h0*m0[2]+g.h1*m0[5]+g.h2*m0[8]);
            float b = g.h0*(g.h0*m1[0]+g.h1*m1[3]+g.h2*m1[6]) + g.h1*(g.h0*m1[1]+g.h1*m1[4]+g.h2*m1[7]) + g.h2*(g.h0*m1[2]+g.h1*m1[5]+g.h2*m1[8]);
            sc[wv][et*28 + 24 + t] = pk2(a, b);
          }
          #pragma unroll
          for (int l = 0; l < 8; l++) senc[wv][et*9 + l] = pk2(g.enc[l], g.enc[l]);
        } else {
          #pragma unroll
          for (int t = 0; t < 4; t++) sc[wv][et*28 + 24 + t] = 0;
          #pragma unroll
          for (int l = 0; l < 8; l++) senc[wv][et*9 + l] = 0;
        }
      }
    }
    __syncthreads();
    {
      const u32* scw = sc[wv];
      const u32* sew = senc[wv];
      #pragma unroll
      for (int s = 0; s < 14; s++) {
        const int m = 4*s + kg;
        const int l = m / 7;
        const int j = m - l*7;
        const uint4 ca = *(const uint4*)&scw[row*28 + j*4];
        const h8 af = mul_enc(ca, sew[row*9 + l]);
        const h8 b0 = as_h8(*(const uint4*)&sB[(s*64 + lane)*4]);
        const h8 b1 = as_h8(*(const uint4*)&sB[((14 + s)*64 + lane)*4]);
        acc0 = __builtin_amdgcn_mfma_f32_16x16x32_f16(af, b0, acc0, 0, 0, 0);
        acc1 = __builtin_amdgcn_mfma_f32_16x16x32_f16(af, b1, acc1, 0, 0, 0);
      }
    }
  }

  float o0 = (acc0[0]+acc0[1])+(acc0[2]+acc0[3]);
  float o1 = (acc1[0]+acc1[1])+(acc1[2]+acc1[3]);
  o0 += __shfl_xor(o0, 16, 64); o0 += __shfl_xor(o0, 32, 64);
  o1 += __shfl_xor(o1, 16, 64); o1 += __shfl_xor(o1, 32, 64);
  if (n < Nn && lane < 16) {
    outA[(size_t)n*32 + lane]      = 0.1f*o0;
    outA[(size_t)n*32 + 16 + lane] = 0.1f*o1;
  }
}

// V: psi_v. per-chunk accs + per-row h-mixing folded into node registers; plain store.
__global__ __launch_bounds__(256, 3) void msgV_csr(
    const float* __restrict__ r_ij, const float* __restrict__ x_a,
    const float* __restrict__ x_v,  const float* __restrict__ x_d,
    const float* __restrict__ P011, const float* __restrict__ P101, const float* __restrict__ P121,
    const float* __restrict__ P211, const float* __restrict__ P111,
    const int* __restrict__ dst,
    const int* __restrict__ row_ptr, const int* __restrict__ sorted, int Nn,
    float* __restrict__ outV)
{
  __shared__ __align__(16) u32 sB[6144];
  __shared__ __align__(16) u32 sxs[4][448];
  __shared__ __align__(16) u32 sY[4][704];
  __shared__ u32 senc[4][144];
  __shared__ float sh[4][48];
  __shared__ int scnt[4];

  for (int i = threadIdx.x; i < 6144; i += 256) {
    const int p = i & 3, ln = (i >> 2) & 63;
    const int n = ln & 15, kgq = ln >> 4;
    float w0 = 0.0f, w1 = 0.0f;
    if (i < 3072) {
      const int step = i >> 8;
      const int k = step*32 + kgq*8 + 2*p;
      const int l = k / 48, ch = k - l*48;
      const int base = n*8 + l;
      if (ch < 32) { w0 = P101[base*32 + ch];      w1 = P101[base*32 + ch + 1]; }
      else         { w0 = P211[base*16 + (ch-32)]; w1 = P211[base*16 + (ch-31)]; }
    } else {
      const int iy = i - 3072;
      const int rest = iy >> 8;
      const int step = rest % 6, tile = rest / 6;
      const int k = step*32 + kgq*8 + 2*p;
      const int l = k / 24, ch = k - l*24;
      const int base = n*8 + l;
      if (tile == 0) {
        if (ch < 16) { w0 = P011[base*16 + ch];      w1 = P011[base*16 + ch + 1]; }
        else         { w0 = P121[base*8 + (ch-16)];  w1 = P121[base*8 + (ch-15)]; }
      } else {
        if (ch < 16) { w0 = P111[base*16 + ch];      w1 = P111[base*16 + ch + 1]; }
      }
    }
    sB[i] = pk2(w0, w1);
  }

  const int wv = threadIdx.x >> 6;
  const int lane = threadIdx.x & 63;
  const int n = blockIdx.x*4 + wv;
  int beg = 0, end = 0;
  if (n < Nn) { beg = row_ptr[n]; end = row_ptr[n+1]; }
  if (lane == 0) scnt[wv] = (end - beg + 15) >> 4;
  __syncthreads();
  const int umax = max(max(scnt[0],scnt[1]), max(scnt[2],scnt[3]));

  const int et = lane >> 2, part = lane & 3;
  const int row = lane & 15, kg = lane >> 4;
  float nv0 = 0.f, nv1 = 0.f, nv2 = 0.f;

  for (int ch = 0; ch < umax; ch++) {
    {
      const int ei = beg + ch*16 + et;
      const int e = (ei < end) ? sorted[ei] : -1;
      Geom g;
      const bool ok = (e >= 0) && geom_of(r_ij, e, g);
      const int nj = ok ? dst[e] : 0;
      if (part == 0) {
        if (ok) {
          const float4* xa4 = (const float4*)(x_a + (size_t)nj*32);
          #pragma unroll
          for (int q = 0; q < 8; q++) {
            float4 f = xa4[q];
            sxs[wv][et*28 + 2*q]     = pk2(f.x, f.y);
            sxs[wv][et*28 + 2*q + 1] = pk2(f.z, f.w);
          }
        } else {
          #pragma unroll
          for (int q = 0; q < 16; q++) sxs[wv][et*28 + q] = 0;
        }
      } else if (part == 1) {
        if (ok) {
          float vb[48];
          const float4* xv4 = (const float4*)(x_v + (size_t)nj*48);
          #pragma unroll
          for (int q = 0; q < 12; q++) { float4 f = xv4[q]; vb[4*q]=f.x; vb[4*q+1]=f.y; vb[4*q+2]=f.z; vb[4*q+3]=f.w; }
          #pragma unroll
          for (int c = 0; c < 3; c++)
            #pragma unroll
            for (int t = 0; t < 8; t++)
              sY[wv][et*44 + c*12 + t] = pk2(vb[6*t + c], vb[6*t + 3 + c]);
          #pragma unroll
          for (int t = 0; t < 8; t++) {
            float a = g.h0*vb[6*t+0] + g.h1*vb[6*t+1] + g.h2*vb[6*t+2];
            float b = g.h0*vb[6*t+3] + g.h1*vb[6*t+4] + g.h2*vb[6*t+5];
            sxs[wv][et*28 + 16 + t] = pk2(a, b);
          }
        } else {
          #pragma unroll
          for (int c = 0; c < 3; c++)
            #pragma unroll
            for (int t = 0; t < 8; t++) sY[wv][et*44 + c*12 + t] = 0;
          #pragma unroll
          for (int t = 0; t < 8; t++) sxs[wv][et*28 + 16 + t] = 0;
        }
      } else if (part == 2) {
        if (ok) {
          float db[72];
          const float4* xd4 = (const float4*)(x_d + (size_t)nj*72);
          #pragma unroll
          for (int q = 0; q < 18; q++) { float4 f = xd4[q]; db[4*q]=f.x; db[4*q+1]=f.y; db[4*q+2]=f.z; db[4*q+3]=f.w; }
          #pragma unroll
          for (int c = 0; c < 3; c++)
            #pragma unroll
            for (int t = 0; t < 4; t++) {
              float a = g.h0*db[9*(2*t)+c]   + g.h1*db[9*(2*t)+3+c]   + g.h2*db[9*(2*t)+6+c];
              float b = g.h0*db[9*(2*t+1)+c] + g.h1*db[9*(2*t+1)+3+c] + g.h2*db[9*(2*t+1)+6+c];
              sY[wv][et*44 + c*12 + 8 + t] = pk2(a, b);
            }
        } else {
          #pragma unroll
          for (int c = 0; c < 3; c++)
            #pragma unroll
            for (int t = 0; t < 4; t++) sY[wv][et*44 + c*12 + 8 + t] = 0;
        }
      } else {
        if (ok) {
          #pragma unroll
          for (int l = 0; l < 8; l++) senc[wv][et*9 + l] = pk2(g.enc[l], g.enc[l]);
          sh[wv][et*3+0] = g.h0; sh[wv][et*3+1] = g.h1; sh[wv][et*3+2] = g.h2;
        } else {
          #pragma unroll
          for (int l = 0; l < 8; l++) senc[wv][et*9 + l] = 0;
          sh[wv][et*3+0] = 0; sh[wv][et*3+1] = 0; sh[wv][et*3+2] = 0;
        }
      }
    }
    __syncthreads();

    const u32* sxw = sxs[wv];
    const u32* syw = sY[wv];
    const u32* sew = senc[wv];

    f4 accS = {0,0,0,0};
    #pragma unroll
    for (int s = 0; s < 12; s++) {
      const int m = 4*s + kg;
      const int l = m / 6;
      const int j = m - l*6;
      const uint4 ca = *(const uint4*)&sxw[row*28 + j*4];
      const h8 af = mul_enc(ca, sew[row*9 + l]);
      const h8 bf = as_h8(*(const uint4*)&sB[(s*64 + lane)*4]);
      accS = __builtin_amdgcn_mfma_f32_16x16x32_f16(af, bf, accS, 0, 0, 0);
    }
    f4 accA[3], accW[3];
    #pragma unroll
    for (int c = 0; c < 3; c++) { accA[c] = f4{0,0,0,0}; accW[c] = f4{0,0,0,0}; }
    #pragma unroll
    for (int c = 0; c < 3; c++) {
      #pragma unroll
      for (int s = 0; s < 6; s++) {
        const int m = 4*s + kg;
        const int l = m / 3;
        const int j = m - l*3;
        const uint4 ca = *(const uint4*)&syw[row*44 + c*12 + j*4];
        const h8 af = mul_enc(ca, sew[row*9 + l]);
        const h8 bA = as_h8(*(const uint4*)&sB[3072 + (s*64 + lane)*4]);
        const h8 bW = as_h8(*(const uint4*)&sB[3072 + ((6 + s)*64 + lane)*4]);
        accA[c] = __builtin_amdgcn_mfma_f32_16x16x32_f16(af, bA, accA[c], 0, 0, 0);
        accW[c] = __builtin_amdgcn_mfma_f32_16x16x32_f16(af, bW, accW[c], 0, 0, 0);
      }
    }
    #pragma unroll
    for (int i = 0; i < 4; i++) {
      const int r = kg*4 + i;
      const float h0 = sh[wv][r*3], h1 = sh[wv][r*3+1], h2 = sh[wv][r*3+2];
      const float sv = accS[i];
      const float A0 = accA[0][i], A1 = accA[1][i], A2 = accA[2][i];
      const float W0 = accW[0][i], W1 = accW[1][i], W2 = accW[2][i];
      nv0 += A0 + (h1*W2 - h2*W1) + h0*sv;
      nv1 += A1 + (h2*W0 - h0*W2) + h1*sv;
      nv2 += A2 + (h0*W1 - h1*W0) + h2*sv;
    }
  }

  nv0 += __shfl_xor(nv0, 16, 64); nv0 += __shfl_xor(nv0, 32, 64);
  nv1 += __shfl_xor(nv1, 16, 64); nv1 += __shfl_xor(nv1, 32, 64);
  nv2 += __shfl_xor(nv2, 16, 64); nv2 += __shfl_xor(nv2, 32, 64);
  if (n < Nn && lane < 16) {
    float* o = outV + (size_t)n*48 + lane*3;
    o[0] = 0.1f*nv0; o[1] = 0.1f*nv1; o[2] = 0.1f*nv2;
  }
}

// D: psi_d. per-chunk accs, per-row Q via shfl_xor(8), node nd[9]; plain store.
__global__ __launch_bounds__(256, 3) void msgD_csr(
    const float* __restrict__ r_ij, const float* __restrict__ x_a,
    const float* __restrict__ x_v,  const float* __restrict__ x_d,
    const float* __restrict__ P022, const float* __restrict__ P202, const float* __restrict__ P112,
    const float* __restrict__ P222, const float* __restrict__ P212,
    const int* __restrict__ dst,
    const int* __restrict__ row_ptr, const int* __restrict__ sorted, int Nn,
    float* __restrict__ outD)
{
  __shared__ __align__(16) u32 sB[4096];
  __shared__ __align__(16) u32 sxa[4][320];
  __shared__ __align__(16) u32 sY[4][704];
  __shared__ __align__(16) u32 sX[4][704];
  __shared__ u32 senc[4][144];
  __shared__ float sh[4][48];
  __shared__ int scnt[4];

  for (int i = threadIdx.x; i < 4096; i += 256) {
    const int p = i & 3, ln = (i >> 2) & 63;
    const int n16 = ln & 15, kgq = ln >> 4;
    float w0 = 0.0f, w1 = 0.0f;
    if (i < 2048) {
      const int step = i >> 8;
      const int k = step*32 + kgq*8 + 2*p;
      const int l = k >> 5, ch = k & 31;
      if (n16 < 8) { const int b = (n16*8 + l)*32 + ch; w0 = P202[b]; w1 = P202[b+1]; }
    } else if (i < 3584) {
      const int step = (i - 2048) >> 8;
      const int k = step*32 + kgq*8 + 2*p;
      const int l = k / 24, ch = k - l*24;
      if (n16 < 8) {
        if (ch < 16) { const int b = (n16*8 + l)*16 + ch;      w0 = P112[b]; w1 = P112[b+1]; }
        else         { const int b = (n16*8 + l)*8 + (ch-16);  w0 = P222[b]; w1 = P222[b+1]; }
      } else {
        const int d_ = n16 - 8;
        if (ch < 16) { const int b = (d_*8 + l)*16 + ch;       w0 = P212[b]; w1 = P212[b+1]; }
      }
    } else {
      const int step = (i - 3584) >> 8;
      const int k = step*32 + kgq*8 + 2*p;
      const int l = k >> 3, bb = k & 7;
      if (n16 < 8) { const int b = (n16*8 + l)*8 + bb; w0 = P022[b]; w1 = P022[b+1]; }
    }
    sB[i] = pk2(w0, w1);
  }

  const int wv = threadIdx.x >> 6;
  const int lane = threadIdx.x & 63;
  const int n = blockIdx.x*4 + wv;
  int beg = 0, end = 0;
  if (n < Nn) { beg = row_ptr[n]; end = row_ptr[n+1]; }
  if (lane == 0) scnt[wv] = (end - beg + 15) >> 4;
  __syncthreads();
  const int umax = max(max(scnt[0],scnt[1]), max(scnt[2],scnt[3]));

  const int et = lane >> 2, part = lane & 3;
  const int row = lane & 15, kg = lane >> 4;
  float nd[9] = {0,0,0,0,0,0,0,0,0};

  for (int ch = 0; ch < umax; ch++) {
    {
      const int ei = beg + ch*16 + et;
      const int e = (ei < end) ? sorted[ei] : -1;
      Geom g;
      const bool ok = (e >= 0) && geom_of(r_ij, e, g);
      const int nj = ok ? dst[e] : 0;
      if (part == 0) {
        if (ok) {
          const float4* xa4 = (const float4*)(x_a + (size_t)nj*32);
          #pragma unroll
          for (int q = 0; q < 8; q++) {
            float4 f = xa4[q];
            sxa[wv][et*20 + 2*q]     = pk2(f.x, f.y);
            sxa[wv][et*20 + 2*q + 1] = pk2(f.z, f.w);
          }
          #pragma unroll
          for (int l = 0; l < 8; l++) senc[wv][et*9 + l] = pk2(g.enc[l], g.enc[l]);
          sh[wv][et*3+0] = g.h0; sh[wv][et*3+1] = g.h1; sh[wv][et*3+2] = g.h2;
        } else {
          #pragma unroll
          for (int q = 0; q < 16; q++) sxa[wv][et*20 + q] = 0;
          #pragma unroll
          for (int l = 0; l < 8; l++) senc[wv][et*9 + l] = 0;
          sh[wv][et*3+0] = 0; sh[wv][et*3+1] = 0; sh[wv][et*3+2] = 0;
        }
      } else if (part == 1) {
        if (ok) {
          float vb[48];
          const float4* xv4 = (const float4*)(x_v + (size_t)nj*48);
          #pragma unroll
          for (int q = 0; q < 12; q++) { float4 f = xv4[q]; vb[4*q]=f.x; vb[4*q+1]=f.y; vb[4*q+2]=f.z; vb[4*q+3]=f.w; }
          #pragma unroll
          for (int c = 0; c < 3; c++)
            #pragma unroll
            for (int t = 0; t < 8; t++)
              sY[wv][et*44 + c*12 + t] = pk2(vb[6*t + c], vb[6*t + 3 + c]);
        } else {
          #pragma unroll
          for (int c = 0; c < 3; c++)
            #pragma unroll
            for (int t = 0; t < 8; t++) sY[wv][et*44 + c*12 + t] = 0;
        }
      } else if (part == 2) {
        if (ok) {
          float db[72];
          const float4* xd4 = (const float4*)(x_d + (size_t)nj*72);
          #pragma unroll
          for (int q = 0; q < 18; q++) { float4 f = xd4[q]; db[4*q]=f.x; db[4*q+1]=f.y; db[4*q+2]=f.z; db[4*q+3]=f.w; }
          #pragma unroll
          for (int c = 0; c < 3; c++)
            #pragma unroll
            for (int t = 0; t < 4; t++) {
              float a = g.h0*db[9*(2*t)+c]   + g.h1*db[9*(2*t)+3+c]   + g.h2*db[9*(2*t)+6+c];
              float b = g.h0*db[9*(2*t+1)+c] + g.h1*db[9*(2*t+1)+3+c] + g.h2*db[9*(2*t+1)+6+c];
              sY[wv][et*44 + c*12 + 8 + t] = pk2(a, b);
            }
        } else {
          #pragma unroll
          for (int c = 0; c < 3; c++)
            #pragma unroll
            for (int t = 0; t < 4; t++) sY[wv][et*44 + c*12 + 8 + t] = 0;
        }
      } else {
        if (ok) {
          float db[72];
          const float4* xd4 = (const float4*)(x_d + (size_t)nj*72);
          #pragma unroll
          for (int q = 0; q < 18; q++) { float4 f = xd4[q]; db[4*q]=f.x; db[4*q+1]=f.y; db[4*q+2]=f.z; db[4*q+3]=f.w; }
          #pragma unroll
          for (int ij = 0; ij < 9; ij++)
            #pragma unroll
            for (int pp = 0; pp < 4; pp++)
              sX[wv][et*44 + ij*4 + pp] = pk2(db[(2*pp)*9 + ij], db[(2*pp+1)*9 + ij]);
        } else {
          #pragma unroll
          for (int q = 0; q < 36; q++) sX[wv][et*44 + q] = 0;
        }
      }
    }
    __syncthreads();

    const u32* saw = sxa[wv];
    const u32* syw = sY[wv];
    const u32* sxw = sX[wv];
    const u32* sew = senc[wv];

    f4 accSd = {0,0,0,0};
    #pragma unroll
    for (int s = 0; s < 8; s++) {
      const int m = 4*s + kg;
      const int l = m >> 2, j = m & 3;
      const uint4 ca = *(const uint4*)&saw[row*20 + j*4];
      const h8 af = mul_enc(ca, sew[row*9 + l]);
      const h8 bf = as_h8(*(const uint4*)&sB[(s*64 + lane)*4]);
      accSd = __builtin_amdgcn_mfma_f32_16x16x32_f16(af, bf, accSd, 0, 0, 0);
    }
    f4 accY[3];
    #pragma unroll
    for (int c = 0; c < 3; c++) accY[c] = f4{0,0,0,0};
    #pragma unroll
    for (int c = 0; c < 3; c++) {
      #pragma unroll
      for (int s = 0; s < 6; s++) {
        const int m = 4*s + kg;
        const int l = m / 3;
        const int j = m - l*3;
        const uint4 ca = *(const uint4*)&syw[row*44 + c*12 + j*4];
        const h8 af = mul_enc(ca, sew[row*9 + l]);
        const h8 bf = as_h8(*(const uint4*)&sB[2048 + (s*64 + lane)*4]);
        accY[c] = __builtin_amdgcn_mfma_f32_16x16x32_f16(af, bf, accY[c], 0, 0, 0);
      }
    }
    f4 accX[9];
    #pragma unroll
    for (int ij = 0; ij < 9; ij++) accX[ij] = f4{0,0,0,0};
    #pragma unroll
    for (int ij = 0; ij < 9; ij++) {
      const uint4 ca = *(const uint4*)&sxw[row*44 + ij*4];
      #pragma unroll
      for (int s = 0; s < 2; s++) {
        const h8 af = mul_enc(ca, sew[row*9 + 4*s + kg]);
        const h8 bf = as_h8(*(const uint4*)&sB[3584 + (s*64 + lane)*4]);
        accX[ij] = __builtin_amdgcn_mfma_f32_16x16x32_f16(af, bf, accX[ij], 0, 0, 0);
      }
    }
    #pragma unroll
    for (int i = 0; i < 4; i++) {
      const int r = kg*4 + i;
      const float h0 = sh[wv][r*3], h1 = sh[wv][r*3+1], h2 = sh[wv][r*3+2];
      const float sd = accSd[i];
      const float A0 = accY[0][i], A1 = accY[1][i], A2 = accY[2][i];
      const float W0 = __shfl_xor(A0, 8, 64);
      const float W1 = __shfl_xor(A1, 8, 64);
      const float W2 = __shfl_xor(A2, 8, 64);
      const float q0 = A0 + (h1*W2 - h2*W1) + h0*sd;
      const float q1 = A1 + (h2*W0 - h0*W2) + h1*sd;
      const float q2 = A2 + (h0*W1 - h1*W0) + h2*sd;
      nd[0] += accX[0][i] + h0*q0;  nd[1] += accX[1][i] + h0*q1;  nd[2] += accX[2][i] + h0*q2;
      nd[3] += accX[3][i] + h1*q0;  nd[4] += accX[4][i] + h1*q1;  nd[5] += accX[5][i] + h1*q2;
      nd[6] += accX[6][i] + h2*q0;  nd[7] += accX[7][i] + h2*q1;  nd[8] += accX[8][i] + h2*q2;
    }
  }

  #pragma unroll
  for (int k = 0; k < 9; k++) {
    nd[k] += __shfl_xor(nd[k], 16, 64);
    nd[k] += __shfl_xor(nd[k], 32, 64);
  }
  if (n < Nn && lane < 8) {
    float* o = outD + (size_t)n*72 + lane*9;
    #pragma unroll
    for (int k = 0; k < 9; k++) o[k] = 0.1f*nd[k];
  }
}

// ======================= scalar fallback (insurance only; runs if ws too small) =======================
__global__ __launch_bounds__(256) void fallback_all(
    const float* __restrict__ r_ij, const float* __restrict__ x_a,
    const float* __restrict__ x_v,  const float* __restrict__ x_d,
    const float* __restrict__ P000, const float* __restrict__ P110, const float* __restrict__ P220,
    const float* __restrict__ P011, const float* __restrict__ P101, const float* __restrict__ P121,
    const float* __restrict__ P211, const float* __restrict__ P111,
    const float* __restrict__ P022, const float* __restrict__ P202, const float* __restrict__ P112,
    const float* __restrict__ P222, const float* __restrict__ P212,
    const int* __restrict__ src, const int* __restrict__ dst, int E,
    float* __restrict__ outA, float* __restrict__ outV, float* __restrict__ outD)
{
  const int e = blockIdx.x*256 + threadIdx.x;
  if (e >= E) return;
  Geom g;
  if (!geom_of(r_ij, e, g)) return;
  const int nj = dst[e], ni = src[e];
  const float* xa = x_a + (size_t)nj*32;
  const float* xv = x_v + (size_t)nj*48;
  const float* xd = x_d + (size_t)nj*72;
  float V0[16],V1[16],V2[16],s1[16],T0[8],T1[8],T2[8],s2[8];
  for (int b = 0; b < 16; b++) {
    V0[b]=xv[3*b]; V1[b]=xv[3*b+1]; V2[b]=xv[3*b+2];
    s1[b]=g.h0*V0[b]+g.h1*V1[b]+g.h2*V2[b];
  }
  for (int b = 0; b < 8; b++) {
    const float* m = xd + 9*b;
    T0[b]=g.h0*m[0]+g.h1*m[3]+g.h2*m[6];
    T1[b]=g.h0*m[1]+g.h1*m[4]+g.h2*m[7];
    T2[b]=g.h0*m[2]+g.h1*m[5]+g.h2*m[8];
    s2[b]=g.h0*T0[b]+g.h1*T1[b]+g.h2*T2[b];
  }
  for (int a = 0; a < 32; a++) {
    float acc = 0;
    for (int l = 0; l < 8; l++) {
      float u = 0;
      for (int b = 0; b < 32; b++) u += P000[(a*8+l)*32+b]*xa[b];
      for (int b = 0; b < 16; b++) u += P110[(a*8+l)*16+b]*s1[b];
      for (int b = 0; b < 8;  b++) u += P220[(a*8+l)*8+b]*s2[b];
      acc += g.enc[l]*u;
    }
    atomicAdd(outA + (size_t)ni*32 + a, 0.1f*acc);
  }
  for (int v = 0; v < 16; v++) {
    float sv=0,A0=0,A1=0,A2=0,W0=0,W1=0,W2=0;
    for (int l = 0; l < 8; l++) {
      const float el = g.enc[l];
      float u=0;
      for (int b=0;b<32;b++) u += P101[(v*8+l)*32+b]*xa[b];
      for (int b=0;b<16;b++) u += P211[(v*8+l)*16+b]*s1[b];
      sv += el*u;
      float a0=0,a1=0,a2=0,w0=0,w1=0,w2=0;
      for (int b=0;b<16;b++){float p=P011[(v*8+l)*16+b]; a0+=p*V0[b];a1+=p*V1[b];a2+=p*V2[b];}
      for (int b=0;b<8;b++){float p=P121[(v*8+l)*8+b]; a0+=p*T0[b];a1+=p*T1[b];a2+=p*T2[b];}
      for (int b=0;b<16;b++){float p=P111[(v*8+l)*16+b]; w0+=p*V0[b];w1+=p*V1[b];w2+=p*V2[b];}
      A0+=el*a0;A1+=el*a1;A2+=el*a2;W0+=el*w0;W1+=el*w1;W2+=el*w2;
    }
    float* o = outV + (size_t)ni*48 + v*3;
    atomicAdd(o+0, 0.1f*(A0 + (g.h1*W2-g.h2*W1) + g.h0*sv));
    atomicAdd(o+1, 0.1f*(A1 + (g.h2*W0-g.h0*W2) + g.h1*sv));
    atomicAdd(o+2, 0.1f*(A2 + (g.h0*W1-g.h1*W0) + g.h2*sv));
  }
  const float hh[3]={g.h0,g.h1,g.h2};
  for (int d = 0; d < 8; d++) {
    float sd=0,A0=0,A1=0,A2=0,W0=0,W1=0,W2=0;
    float w[8]={0,0,0,0,0,0,0,0};
    for (int l = 0; l < 8; l++) {
      const float el = g.enc[l];
      float u=0;
      for (int b=0;b<32;b++) u += P202[(d*8+l)*32+b]*xa[b];
      sd += el*u;
      float a0=0,a1=0,a2=0,w0=0,w1=0,w2=0;
      for (int b=0;b<16;b++){float p=P112[(d*8+l)*16+b]; a0+=p*V0[b];a1+=p*V1[b];a2+=p*V2[b];}
      for (int b=0;b<8;b++){float p=P222[(d*8+l)*8+b]; a0+=p*T0[b];a1+=p*T1[b];a2+=p*T2[b];}
      for (int b=0;b<16;b++){float p=P212[(d*8+l)*16+b]; w0+=p*V0[b];w1+=p*V1[b];w2+=p*V2[b];}
      A0+=el*a0;A1+=el*a1;A2+=el*a2;W0+=el*w0;W1+=el*w1;W2+=el*w2;
      for (int b=0;b<8;b++) w[b]+=el*P022[(d*8+l)*8+b];
    }
    const float q[3] = { A0+(g.h1*W2-g.h2*W1)+g.h0*sd,
                         A1+(g.h2*W0-g.h0*W2)+g.h1*sd,
                         A2+(g.h0*W1-g.h1*W0)+g.h2*sd };
    float* o = outD + (size_t)ni*72 + d*9;
    for (int ii = 0; ii < 3; ii++)
      for (int jj = 0; jj < 3; jj++) {
        float acc = 0;
        for (int b = 0; b < 8; b++) acc += w[b]*xd[9*b + ii*3 + jj];
        atomicAdd(o + ii*3 + jj, 0.1f*(acc + hh[ii]*q[jj]));
      }
  }
}

extern "C" void kernel_launch(void* const* d_in, const int* in_sizes, int n_in,
                              void* d_out, int out_size, void* d_ws, size_t ws_size,
                              hipStream_t stream) {
  const float* r_ij = (const float*)d_in[0];
  const float* x_a  = (const float*)d_in[1];
  const float* x_v  = (const float*)d_in[2];
  const float* x_d  = (const float*)d_in[3];
  const float* P000 = (const float*)d_in[4];
  const float* P110 = (const float*)d_in[5];
  const float* P220 = (const float*)d_in[6];
  const float* P011 = (const float*)d_in[7];
  const float* P101 = (const float*)d_in[8];
  const float* P121 = (const float*)d_in[9];
  const float* P211 = (const float*)d_in[10];
  const float* P111 = (const float*)d_in[11];
  const float* P022 = (const float*)d_in[12];
  const float* P202 = (const float*)d_in[13];
  const float* P112 = (const float*)d_in[14];
  const float* P222 = (const float*)d_in[15];
  const float* P212 = (const float*)d_in[16];
  const int* src = (const int*)d_in[17];
  const int* dst = (const int*)d_in[18];

  const int E  = in_sizes[17];
  const int Nn = in_sizes[1] / 32;
  float* out  = (float*)d_out;
  float* outA = out;
  float* outV = out + (size_t)Nn*32;
  float* outD = out + (size_t)Nn*80;

  const size_t need = 4ull * (2ull*(size_t)Nn + 1 + (size_t)E);
  if (ws_size >= need) {
    int* hist    = (int*)d_ws;          // N counters, becomes scatter cursor
    int* row_ptr = hist + Nn;           // N+1
    int* sorted  = row_ptr + Nn + 1;    // E
    hipMemsetAsync(hist, 0, (size_t)Nn*sizeof(int), stream);
    hist_k   <<<(E + 255)/256, 256, 0, stream>>>(r_ij, src, E, hist);
    scan_k   <<<1, 256, 0, stream>>>(hist, Nn, row_ptr);
    scatter_k<<<(E + 255)/256, 256, 0, stream>>>(r_ij, src, E, hist, sorted);

    const int nb = (Nn + 3) / 4;
    msgS_csr<<<nb, 256, 0, stream>>>(r_ij, x_a, x_v, x_d,
        P000, P110, P220, dst, row_ptr, sorted, Nn, outA);
    msgV_csr<<<nb, 256, 0, stream>>>(r_ij, x_a, x_v, x_d,
        P011, P101, P121, P211, P111, dst, row_ptr, sorted, Nn, outV);
    msgD_csr<<<nb, 256, 0, stream>>>(r_ij, x_a, x_v, x_d,
        P022, P202, P112, P222, P212, dst, row_ptr, sorted, Nn, outD);
  } else {
    hipMemsetAsync(d_out, 0, (size_t)out_size * sizeof(float), stream);
    fallback_all<<<(E + 255)/256, 256, 0, stream>>>(r_ij, x_a, x_v, x_d,
        P000, P110, P220, P011, P101, P121, P211, P111,
        P022, P202, P112, P222, P212, src, dst, E, outA, outV, outD);
  }
}

// Round 9
// 290.135 us; speedup vs baseline: 8.9205x; 1.6311x over previous
//
#include <hip/hip_runtime.h>

#define PI_F 3.14159265358979323846f

typedef _Float16 h8 __attribute__((ext_vector_type(8)));
typedef _Float16 h2v __attribute__((ext_vector_type(2)));
typedef float f4 __attribute__((ext_vector_type(4)));
typedef unsigned int u32;

struct Geom { float enc[8]; float h0, h1, h2; };

__device__ __forceinline__ bool geom_of(const float* __restrict__ r, int e, Geom& g) {
  const float rx = r[3*e], ry = r[3*e+1], rz = r[3*e+2];
  const float xsq = (rx*rx + ry*ry + rz*rz) * (1.0f/2.5f);
  const float cut = 1.0f - xsq;
  if (cut <= 0.0f) return false;
  const float c1 = cosf(PI_F * sqrtf(xsq));
  g.enc[0] = cut; g.enc[1] = c1*cut;
  float cp = 1.0f, cc = c1;
  #pragma unroll
  for (int n = 2; n < 8; n++) { float cn = 2.0f*c1*cc - cp; cp = cc; cc = cn; g.enc[n] = cn*cut; }
  const float s = 7.0f/2.5f;
  const float yx = rx*s, yy = ry*s, yz = rz*s;
  const float inv = rsqrtf(1.0f + yx*yx + yy*yy + yz*yz);
  g.h0 = yx*inv; g.h1 = yy*inv; g.h2 = yz*inv;
  return true;
}

__device__ __forceinline__ u32 pk2(float a, float b) {
  union { h2v h; u32 u; } r;
  r.h.x = (_Float16)a; r.h.y = (_Float16)b;
  return r.u;
}

__device__ __forceinline__ h8 mul_enc(uint4 c, u32 e) {
  union { uint4 u; h2v p[4]; } C; C.u = c;
  union { u32 u; h2v h; } E; E.u = e;
  union { h2v p[4]; h8 v; } R;
  #pragma unroll
  for (int i = 0; i < 4; i++) R.p[i] = C.p[i] * E.h;
  return R.v;
}

__device__ __forceinline__ h8 as_h8(uint4 c) { union { uint4 u; h8 v; } r; r.u = c; return r.v; }

// wave-local LDS fence: same-wave DS ops are in-order; this makes cross-lane
// writes visible without a block barrier (rule #18: sched_barrier after asm waitcnt).
__device__ __forceinline__ void wave_lds_fence() {
  asm volatile("s_waitcnt lgkmcnt(0)" ::: "memory");
  __builtin_amdgcn_sched_barrier(0);
}

// ======================= CSR build =======================
__global__ __launch_bounds__(256) void hist_k(const float* __restrict__ r, const int* __restrict__ src,
                                              int E, int* __restrict__ hist) {
  int e = blockIdx.x * 256 + threadIdx.x;
  if (e >= E) return;
  float rx = r[3*e], ry = r[3*e+1], rz = r[3*e+2];
  float xsq = (rx*rx + ry*ry + rz*rz) * (1.0f/2.5f);
  if (xsq < 1.0f) atomicAdd(&hist[src[e]], 1);
}

__global__ __launch_bounds__(256) void scan_k(int* __restrict__ hist, int Nn, int* __restrict__ row_ptr) {
  __shared__ int part[256];
  const int t = threadIdx.x;
  const int chunk = (Nn + 255) / 256;
  const int i0 = t * chunk;
  int s = 0;
  for (int j = 0; j < chunk; j++) { int i = i0 + j; if (i < Nn) s += hist[i]; }
  part[t] = s;
  __syncthreads();
  for (int off = 1; off < 256; off <<= 1) {
    int v = (t >= off) ? part[t - off] : 0;
    __syncthreads();
    part[t] += v;
    __syncthreads();
  }
  int run = part[t] - s;
  for (int j = 0; j < chunk; j++) {
    int i = i0 + j;
    if (i < Nn) { int h = hist[i]; row_ptr[i] = run; hist[i] = run; run += h; }
  }
  if (t == 255) row_ptr[Nn] = part[255];
}

__global__ __launch_bounds__(256) void scatter_k(const float* __restrict__ r, const int* __restrict__ src,
                                                 int E, int* __restrict__ cur, int* __restrict__ sorted) {
  int e = blockIdx.x * 256 + threadIdx.x;
  if (e >= E) return;
  float rx = r[3*e], ry = r[3*e+1], rz = r[3*e+2];
  float xsq = (rx*rx + ry*ry + rz*rz) * (1.0f/2.5f);
  if (xsq < 1.0f) {
    int p = atomicAdd(&cur[src[e]], 1);
    sorted[p] = e;
  }
}

// ======================= persistent wave-per-node kernels =======================
// S: psi_a
__global__ __launch_bounds__(256, 4) void msgS_csr(
    const float* __restrict__ r_ij, const float* __restrict__ x_a,
    const float* __restrict__ x_v,  const float* __restrict__ x_d,
    const float* __restrict__ P000, const float* __restrict__ P110, const float* __restrict__ P220,
    const int* __restrict__ dst,
    const int* __restrict__ row_ptr, const int* __restrict__ sorted, int Nn,
    float* __restrict__ outA)
{
  __shared__ __align__(16) u32 sB[7168];
  __shared__ __align__(16) u32 sc[4][448];
  __shared__ u32 senc[4][144];

  for (int i = threadIdx.x; i < 7168; i += 256) {
    const int p = i & 3, ln = (i >> 2) & 63, rest = i >> 8;
    const int step = rest % 14, tile = rest / 14;
    const int k = step*32 + (ln >> 4)*8 + 2*p;
    const int n = tile*16 + (ln & 15);
    const int l = k / 56, b = k - l*56;
    const int base = n*8 + l;
    float w0, w1;
    if (b < 32)      { w0 = P000[base*32 + b];      w1 = P000[base*32 + b + 1]; }
    else if (b < 48) { w0 = P110[base*16 + (b-32)]; w1 = P110[base*16 + (b-31)]; }
    else             { w0 = P220[base*8  + (b-48)]; w1 = P220[base*8  + (b-47)]; }
    sB[i] = pk2(w0, w1);
  }
  __syncthreads();

  const int wv = threadIdx.x >> 6;
  const int lane = threadIdx.x & 63;
  const int et = lane >> 2, part = lane & 3;
  const int row = lane & 15, kg = lane >> 4;
  const int W = gridDim.x * 4;

  for (int n = blockIdx.x*4 + wv; n < Nn; n += W) {
    const int beg = row_ptr[n], end = row_ptr[n+1];
    const int nch = (end - beg + 15) >> 4;
    f4 acc0 = {0,0,0,0}, acc1 = {0,0,0,0};

    for (int ch = 0; ch < nch; ch++) {
      const int ei = beg + ch*16 + et;
      const int e = (ei < end) ? sorted[ei] : -1;
      Geom g;
      const bool ok = (e >= 0) && geom_of(r_ij, e, g);
      const int nj = ok ? dst[e] : 0;
      if (part <= 1) {
        if (ok) {
          const float4* xa4 = (const float4*)(x_a + (size_t)nj*32);
          #pragma unroll
          for (int q = 0; q < 4; q++) {
            float4 f = xa4[part*4 + q];
            sc[wv][et*28 + part*8 + 2*q]     = pk2(f.x, f.y);
            sc[wv][et*28 + part*8 + 2*q + 1] = pk2(f.z, f.w);
          }
        } else {
          #pragma unroll
          for (int q = 0; q < 8; q++) sc[wv][et*28 + part*8 + q] = 0;
        }
      } else if (part == 2) {
        if (ok) {
          float vb[48];
          const float4* xv4 = (const float4*)(x_v + (size_t)nj*48);
          #pragma unroll
          for (int q = 0; q < 12; q++) { float4 f = xv4[q]; vb[4*q]=f.x; vb[4*q+1]=f.y; vb[4*q+2]=f.z; vb[4*q+3]=f.w; }
          #pragma unroll
          for (int t = 0; t < 8; t++) {
            float a = g.h0*vb[6*t+0] + g.h1*vb[6*t+1] + g.h2*vb[6*t+2];
            float b = g.h0*vb[6*t+3] + g.h1*vb[6*t+4] + g.h2*vb[6*t+5];
            sc[wv][et*28 + 16 + t] = pk2(a, b);
          }
        } else {
          #pragma unroll
          for (int t = 0; t < 8; t++) sc[wv][et*28 + 16 + t] = 0;
        }
      } else {
        if (ok) {
          float db[72];
          const float4* xd4 = (const float4*)(x_d + (size_t)nj*72);
          #pragma unroll
          for (int q = 0; q < 18; q++) { float4 f = xd4[q]; db[4*q]=f.x; db[4*q+1]=f.y; db[4*q+2]=f.z; db[4*q+3]=f.w; }
          #pragma unroll
          for (int t = 0; t < 4; t++) {
            const float* m0 = db + 9*(2*t);
            const float* m1 = db + 9*(2*t+1);
            float a = g.h0*(g.h0*m0[0]+g.h1*m0[3]+g.h2*m0[6]) + g.h1*(g.h0*m0[1]+g.h1*m0[4]+g.h2*m0[7]) + g.h2*(g.h0*m0[2]+g.h1*m0[5]+g.h2*m0[8]);
            float b = g.h0*(g.h0*m1[0]+g.h1*m1[3]+g.h2*m1[6]) + g.h1*(g.h0*m1[1]+g.h1*m1[4]+g.h2*m1[7]) + g.h2*(g.h0*m1[2]+g.h1*m1[5]+g.h2*m1[8]);
            sc[wv][et*28 + 24 + t] = pk2(a, b);
          }
          #pragma unroll
          for (int l = 0; l < 8; l++) senc[wv][et*9 + l] = pk2(g.enc[l], g.enc[l]);
        } else {
          #pragma unroll
          for (int t = 0; t < 4; t++) sc[wv][et*28 + 24 + t] = 0;
          #pragma unroll
          for (int l = 0; l < 8; l++) senc[wv][et*9 + l] = 0;
        }
      }
      wave_lds_fence();
      {
        const u32* scw = sc[wv];
        const u32* sew = senc[wv];
        #pragma unroll
        for (int s = 0; s < 14; s++) {
          const int m = 4*s + kg;
          const int l = m / 7;
          const int j = m - l*7;
          const uint4 ca = *(const uint4*)&scw[row*28 + j*4];
          const h8 af = mul_enc(ca, sew[row*9 + l]);
          const h8 b0 = as_h8(*(const uint4*)&sB[(s*64 + lane)*4]);
          const h8 b1 = as_h8(*(const uint4*)&sB[((14 + s)*64 + lane)*4]);
          acc0 = __builtin_amdgcn_mfma_f32_16x16x32_f16(af, b0, acc0, 0, 0, 0);
          acc1 = __builtin_amdgcn_mfma_f32_16x16x32_f16(af, b1, acc1, 0, 0, 0);
        }
      }
    }

    float o0 = (acc0[0]+acc0[1])+(acc0[2]+acc0[3]);
    float o1 = (acc1[0]+acc1[1])+(acc1[2]+acc1[3]);
    o0 += __shfl_xor(o0, 16, 64); o0 += __shfl_xor(o0, 32, 64);
    o1 += __shfl_xor(o1, 16, 64); o1 += __shfl_xor(o1, 32, 64);
    if (lane < 16) {
      outA[(size_t)n*32 + lane]      = 0.1f*o0;
      outA[(size_t)n*32 + 16 + lane] = 0.1f*o1;
    }
  }
}

// V: psi_v
__global__ __launch_bounds__(256, 3) void msgV_csr(
    const float* __restrict__ r_ij, const float* __restrict__ x_a,
    const float* __restrict__ x_v,  const float* __restrict__ x_d,
    const float* __restrict__ P011, const float* __restrict__ P101, const float* __restrict__ P121,
    const float* __restrict__ P211, const float* __restrict__ P111,
    const int* __restrict__ dst,
    const int* __restrict__ row_ptr, const int* __restrict__ sorted, int Nn,
    float* __restrict__ outV)
{
  __shared__ __align__(16) u32 sB[6144];
  __shared__ __align__(16) u32 sxs[4][448];
  __shared__ __align__(16) u32 sY[4][704];
  __shared__ u32 senc[4][144];
  __shared__ float sh[4][48];

  for (int i = threadIdx.x; i < 6144; i += 256) {
    const int p = i & 3, ln = (i >> 2) & 63;
    const int n = ln & 15, kgq = ln >> 4;
    float w0 = 0.0f, w1 = 0.0f;
    if (i < 3072) {
      const int step = i >> 8;
      const int k = step*32 + kgq*8 + 2*p;
      const int l = k / 48, ch = k - l*48;
      const int base = n*8 + l;
      if (ch < 32) { w0 = P101[base*32 + ch];      w1 = P101[base*32 + ch + 1]; }
      else         { w0 = P211[base*16 + (ch-32)]; w1 = P211[base*16 + (ch-31)]; }
    } else {
      const int iy = i - 3072;
      const int rest = iy >> 8;
      const int step = rest % 6, tile = rest / 6;
      const int k = step*32 + kgq*8 + 2*p;
      const int l = k / 24, ch = k - l*24;
      const int base = n*8 + l;
      if (tile == 0) {
        if (ch < 16) { w0 = P011[base*16 + ch];      w1 = P011[base*16 + ch + 1]; }
        else         { w0 = P121[base*8 + (ch-16)];  w1 = P121[base*8 + (ch-15)]; }
      } else {
        if (ch < 16) { w0 = P111[base*16 + ch];      w1 = P111[base*16 + ch + 1]; }
      }
    }
    sB[i] = pk2(w0, w1);
  }
  __syncthreads();

  const int wv = threadIdx.x >> 6;
  const int lane = threadIdx.x & 63;
  const int et = lane >> 2, part = lane & 3;
  const int row = lane & 15, kg = lane >> 4;
  const int W = gridDim.x * 4;

  for (int n = blockIdx.x*4 + wv; n < Nn; n += W) {
    const int beg = row_ptr[n], end = row_ptr[n+1];
    const int nch = (end - beg + 15) >> 4;
    float nv0 = 0.f, nv1 = 0.f, nv2 = 0.f;

    for (int ch = 0; ch < nch; ch++) {
      const int ei = beg + ch*16 + et;
      const int e = (ei < end) ? sorted[ei] : -1;
      Geom g;
      const bool ok = (e >= 0) && geom_of(r_ij, e, g);
      const int nj = ok ? dst[e] : 0;
      if (part == 0) {
        if (ok) {
          const float4* xa4 = (const float4*)(x_a + (size_t)nj*32);
          #pragma unroll
          for (int q = 0; q < 8; q++) {
            float4 f = xa4[q];
            sxs[wv][et*28 + 2*q]     = pk2(f.x, f.y);
            sxs[wv][et*28 + 2*q + 1] = pk2(f.z, f.w);
          }
        } else {
          #pragma unroll
          for (int q = 0; q < 16; q++) sxs[wv][et*28 + q] = 0;
        }
      } else if (part == 1) {
        if (ok) {
          float vb[48];
          const float4* xv4 = (const float4*)(x_v + (size_t)nj*48);
          #pragma unroll
          for (int q = 0; q < 12; q++) { float4 f = xv4[q]; vb[4*q]=f.x; vb[4*q+1]=f.y; vb[4*q+2]=f.z; vb[4*q+3]=f.w; }
          #pragma unroll
          for (int c = 0; c < 3; c++)
            #pragma unroll
            for (int t = 0; t < 8; t++)
              sY[wv][et*44 + c*12 + t] = pk2(vb[6*t + c], vb[6*t + 3 + c]);
          #pragma unroll
          for (int t = 0; t < 8; t++) {
            float a = g.h0*vb[6*t+0] + g.h1*vb[6*t+1] + g.h2*vb[6*t+2];
            float b = g.h0*vb[6*t+3] + g.h1*vb[6*t+4] + g.h2*vb[6*t+5];
            sxs[wv][et*28 + 16 + t] = pk2(a, b);
          }
        } else {
          #pragma unroll
          for (int c = 0; c < 3; c++)
            #pragma unroll
            for (int t = 0; t < 8; t++) sY[wv][et*44 + c*12 + t] = 0;
          #pragma unroll
          for (int t = 0; t < 8; t++) sxs[wv][et*28 + 16 + t] = 0;
        }
      } else if (part == 2) {
        if (ok) {
          float db[72];
          const float4* xd4 = (const float4*)(x_d + (size_t)nj*72);
          #pragma unroll
          for (int q = 0; q < 18; q++) { float4 f = xd4[q]; db[4*q]=f.x; db[4*q+1]=f.y; db[4*q+2]=f.z; db[4*q+3]=f.w; }
          #pragma unroll
          for (int c = 0; c < 3; c++)
            #pragma unroll
            for (int t = 0; t < 4; t++) {
              float a = g.h0*db[9*(2*t)+c]   + g.h1*db[9*(2*t)+3+c]   + g.h2*db[9*(2*t)+6+c];
              float b = g.h0*db[9*(2*t+1)+c] + g.h1*db[9*(2*t+1)+3+c] + g.h2*db[9*(2*t+1)+6+c];
              sY[wv][et*44 + c*12 + 8 + t] = pk2(a, b);
            }
        } else {
          #pragma unroll
          for (int c = 0; c < 3; c++)
            #pragma unroll
            for (int t = 0; t < 4; t++) sY[wv][et*44 + c*12 + 8 + t] = 0;
        }
      } else {
        if (ok) {
          #pragma unroll
          for (int l = 0; l < 8; l++) senc[wv][et*9 + l] = pk2(g.enc[l], g.enc[l]);
          sh[wv][et*3+0] = g.h0; sh[wv][et*3+1] = g.h1; sh[wv][et*3+2] = g.h2;
        } else {
          #pragma unroll
          for (int l = 0; l < 8; l++) senc[wv][et*9 + l] = 0;
          sh[wv][et*3+0] = 0; sh[wv][et*3+1] = 0; sh[wv][et*3+2] = 0;
        }
      }
      wave_lds_fence();

      const u32* sxw = sxs[wv];
      const u32* syw = sY[wv];
      const u32* sew = senc[wv];

      f4 accS = {0,0,0,0};
      #pragma unroll
      for (int s = 0; s < 12; s++) {
        const int m = 4*s + kg;
        const int l = m / 6;
        const int j = m - l*6;
        const uint4 ca = *(const uint4*)&sxw[row*28 + j*4];
        const h8 af = mul_enc(ca, sew[row*9 + l]);
        const h8 bf = as_h8(*(const uint4*)&sB[(s*64 + lane)*4]);
        accS = __builtin_amdgcn_mfma_f32_16x16x32_f16(af, bf, accS, 0, 0, 0);
      }
      f4 accA[3], accW[3];
      #pragma unroll
      for (int c = 0; c < 3; c++) { accA[c] = f4{0,0,0,0}; accW[c] = f4{0,0,0,0}; }
      #pragma unroll
      for (int c = 0; c < 3; c++) {
        #pragma unroll
        for (int s = 0; s < 6; s++) {
          const int m = 4*s + kg;
          const int l = m / 3;
          const int j = m - l*3;
          const uint4 ca = *(const uint4*)&syw[row*44 + c*12 + j*4];
          const h8 af = mul_enc(ca, sew[row*9 + l]);
          const h8 bA = as_h8(*(const uint4*)&sB[3072 + (s*64 + lane)*4]);
          const h8 bW = as_h8(*(const uint4*)&sB[3072 + ((6 + s)*64 + lane)*4]);
          accA[c] = __builtin_amdgcn_mfma_f32_16x16x32_f16(af, bA, accA[c], 0, 0, 0);
          accW[c] = __builtin_amdgcn_mfma_f32_16x16x32_f16(af, bW, accW[c], 0, 0, 0);
        }
      }
      #pragma unroll
      for (int i = 0; i < 4; i++) {
        const int r = kg*4 + i;
        const float h0 = sh[wv][r*3], h1 = sh[wv][r*3+1], h2 = sh[wv][r*3+2];
        const float sv = accS[i];
        const float A0 = accA[0][i], A1 = accA[1][i], A2 = accA[2][i];
        const float W0 = accW[0][i], W1 = accW[1][i], W2 = accW[2][i];
        nv0 += A0 + (h1*W2 - h2*W1) + h0*sv;
        nv1 += A1 + (h2*W0 - h0*W2) + h1*sv;
        nv2 += A2 + (h0*W1 - h1*W0) + h2*sv;
      }
    }

    nv0 += __shfl_xor(nv0, 16, 64); nv0 += __shfl_xor(nv0, 32, 64);
    nv1 += __shfl_xor(nv1, 16, 64); nv1 += __shfl_xor(nv1, 32, 64);
    nv2 += __shfl_xor(nv2, 16, 64); nv2 += __shfl_xor(nv2, 32, 64);
    if (lane < 16) {
      float* o = outV + (size_t)n*48 + lane*3;
      o[0] = 0.1f*nv0; o[1] = 0.1f*nv1; o[2] = 0.1f*nv2;
    }
  }
}

// D: psi_d
__global__ __launch_bounds__(256, 3) void msgD_csr(
    const float* __restrict__ r_ij, const float* __restrict__ x_a,
    const float* __restrict__ x_v,  const float* __restrict__ x_d,
    const float* __restrict__ P022, const float* __restrict__ P202, const float* __restrict__ P112,
    const float* __restrict__ P222, const float* __restrict__ P212,
    const int* __restrict__ dst,
    const int* __restrict__ row_ptr, const int* __restrict__ sorted, int Nn,
    float* __restrict__ outD)
{
  __shared__ __align__(16) u32 sB[4096];
  __shared__ __align__(16) u32 sxa[4][320];
  __shared__ __align__(16) u32 sY[4][704];
  __shared__ __align__(16) u32 sX[4][704];
  __shared__ u32 senc[4][144];
  __shared__ float sh[4][48];

  for (int i = threadIdx.x; i < 4096; i += 256) {
    const int p = i & 3, ln = (i >> 2) & 63;
    const int n16 = ln & 15, kgq = ln >> 4;
    float w0 = 0.0f, w1 = 0.0f;
    if (i < 2048) {
      const int step = i >> 8;
      const int k = step*32 + kgq*8 + 2*p;
      const int l = k >> 5, ch = k & 31;
      if (n16 < 8) { const int b = (n16*8 + l)*32 + ch; w0 = P202[b]; w1 = P202[b+1]; }
    } else if (i < 3584) {
      const int step = (i - 2048) >> 8;
      const int k = step*32 + kgq*8 + 2*p;
      const int l = k / 24, ch = k - l*24;
      if (n16 < 8) {
        if (ch < 16) { const int b = (n16*8 + l)*16 + ch;      w0 = P112[b]; w1 = P112[b+1]; }
        else         { const int b = (n16*8 + l)*8 + (ch-16);  w0 = P222[b]; w1 = P222[b+1]; }
      } else {
        const int d_ = n16 - 8;
        if (ch < 16) { const int b = (d_*8 + l)*16 + ch;       w0 = P212[b]; w1 = P212[b+1]; }
      }
    } else {
      const int step = (i - 3584) >> 8;
      const int k = step*32 + kgq*8 + 2*p;
      const int l = k >> 3, bb = k & 7;
      if (n16 < 8) { const int b = (n16*8 + l)*8 + bb; w0 = P022[b]; w1 = P022[b+1]; }
    }
    sB[i] = pk2(w0, w1);
  }
  __syncthreads();

  const int wv = threadIdx.x >> 6;
  const int lane = threadIdx.x & 63;
  const int et = lane >> 2, part = lane & 3;
  const int row = lane & 15, kg = lane >> 4;
  const int W = gridDim.x * 4;

  for (int n = blockIdx.x*4 + wv; n < Nn; n += W) {
    const int beg = row_ptr[n], end = row_ptr[n+1];
    const int nch = (end - beg + 15) >> 4;
    float nd[9] = {0,0,0,0,0,0,0,0,0};

    for (int ch = 0; ch < nch; ch++) {
      const int ei = beg + ch*16 + et;
      const int e = (ei < end) ? sorted[ei] : -1;
      Geom g;
      const bool ok = (e >= 0) && geom_of(r_ij, e, g);
      const int nj = ok ? dst[e] : 0;
      if (part == 0) {
        if (ok) {
          const float4* xa4 = (const float4*)(x_a + (size_t)nj*32);
          #pragma unroll
          for (int q = 0; q < 8; q++) {
            float4 f = xa4[q];
            sxa[wv][et*20 + 2*q]     = pk2(f.x, f.y);
            sxa[wv][et*20 + 2*q + 1] = pk2(f.z, f.w);
          }
          #pragma unroll
          for (int l = 0; l < 8; l++) senc[wv][et*9 + l] = pk2(g.enc[l], g.enc[l]);
          sh[wv][et*3+0] = g.h0; sh[wv][et*3+1] = g.h1; sh[wv][et*3+2] = g.h2;
        } else {
          #pragma unroll
          for (int q = 0; q < 16; q++) sxa[wv][et*20 + q] = 0;
          #pragma unroll
          for (int l = 0; l < 8; l++) senc[wv][et*9 + l] = 0;
          sh[wv][et*3+0] = 0; sh[wv][et*3+1] = 0; sh[wv][et*3+2] = 0;
        }
      } else if (part == 1) {
        if (ok) {
          float vb[48];
          const float4* xv4 = (const float4*)(x_v + (size_t)nj*48);
          #pragma unroll
          for (int q = 0; q < 12; q++) { float4 f = xv4[q]; vb[4*q]=f.x; vb[4*q+1]=f.y; vb[4*q+2]=f.z; vb[4*q+3]=f.w; }
          #pragma unroll
          for (int c = 0; c < 3; c++)
            #pragma unroll
            for (int t = 0; t < 8; t++)
              sY[wv][et*44 + c*12 + t] = pk2(vb[6*t + c], vb[6*t + 3 + c]);
        } else {
          #pragma unroll
          for (int c = 0; c < 3; c++)
            #pragma unroll
            for (int t = 0; t < 8; t++) sY[wv][et*44 + c*12 + t] = 0;
        }
      } else if (part == 2) {
        if (ok) {
          float db[72];
          const float4* xd4 = (const float4*)(x_d + (size_t)nj*72);
          #pragma unroll
          for (int q = 0; q < 18; q++) { float4 f = xd4[q]; db[4*q]=f.x; db[4*q+1]=f.y; db[4*q+2]=f.z; db[4*q+3]=f.w; }
          #pragma unroll
          for (int c = 0; c < 3; c++)
            #pragma unroll
            for (int t = 0; t < 4; t++) {
              float a = g.h0*db[9*(2*t)+c]   + g.h1*db[9*(2*t)+3+c]   + g.h2*db[9*(2*t)+6+c];
              float b = g.h0*db[9*(2*t+1)+c] + g.h1*db[9*(2*t+1)+3+c] + g.h2*db[9*(2*t+1)+6+c];
              sY[wv][et*44 + c*12 + 8 + t] = pk2(a, b);
            }
        } else {
          #pragma unroll
          for (int c = 0; c < 3; c++)
            #pragma unroll
            for (int t = 0; t < 4; t++) sY[wv][et*44 + c*12 + 8 + t] = 0;
        }
      } else {
        if (ok) {
          float db[72];
          const float4* xd4 = (const float4*)(x_d + (size_t)nj*72);
          #pragma unroll
          for (int q = 0; q < 18; q++) { float4 f = xd4[q]; db[4*q]=f.x; db[4*q+1]=f.y; db[4*q+2]=f.z; db[4*q+3]=f.w; }
          #pragma unroll
          for (int ij = 0; ij < 9; ij++)
            #pragma unroll
            for (int pp = 0; pp < 4; pp++)
              sX[wv][et*44 + ij*4 + pp] = pk2(db[(2*pp)*9 + ij], db[(2*pp+1)*9 + ij]);
        } else {
          #pragma unroll
          for (int q = 0; q < 36; q++) sX[wv][et*44 + q] = 0;
        }
      }
      wave_lds_fence();

      const u32* saw = sxa[wv];
      const u32* syw = sY[wv];
      const u32* sxw = sX[wv];
      const u32* sew = senc[wv];

      f4 accSd = {0,0,0,0};
      #pragma unroll
      for (int s = 0; s < 8; s++) {
        const int m = 4*s + kg;
        const int l = m >> 2, j = m & 3;
        const uint4 ca = *(const uint4*)&saw[row*20 + j*4];
        const h8 af = mul_enc(ca, sew[row*9 + l]);
        const h8 bf = as_h8(*(const uint4*)&sB[(s*64 + lane)*4]);
        accSd = __builtin_amdgcn_mfma_f32_16x16x32_f16(af, bf, accSd, 0, 0, 0);
      }
      f4 accY[3];
      #pragma unroll
      for (int c = 0; c < 3; c++) accY[c] = f4{0,0,0,0};
      #pragma unroll
      for (int c = 0; c < 3; c++) {
        #pragma unroll
        for (int s = 0; s < 6; s++) {
          const int m = 4*s + kg;
          const int l = m / 3;
          const int j = m - l*3;
          const uint4 ca = *(const uint4*)&syw[row*44 + c*12 + j*4];
          const h8 af = mul_enc(ca, sew[row*9 + l]);
          const h8 bf = as_h8(*(const uint4*)&sB[2048 + (s*64 + lane)*4]);
          accY[c] = __builtin_amdgcn_mfma_f32_16x16x32_f16(af, bf, accY[c], 0, 0, 0);
        }
      }
      f4 accX[9];
      #pragma unroll
      for (int ij = 0; ij < 9; ij++) accX[ij] = f4{0,0,0,0};
      #pragma unroll
      for (int ij = 0; ij < 9; ij++) {
        const uint4 ca = *(const uint4*)&sxw[row*44 + ij*4];
        #pragma unroll
        for (int s = 0; s < 2; s++) {
          const h8 af = mul_enc(ca, sew[row*9 + 4*s + kg]);
          const h8 bf = as_h8(*(const uint4*)&sB[3584 + (s*64 + lane)*4]);
          accX[ij] = __builtin_amdgcn_mfma_f32_16x16x32_f16(af, bf, accX[ij], 0, 0, 0);
        }
      }
      #pragma unroll
      for (int i = 0; i < 4; i++) {
        const int r = kg*4 + i;
        const float h0 = sh[wv][r*3], h1 = sh[wv][r*3+1], h2 = sh[wv][r*3+2];
        const float sd = accSd[i];
        const float A0 = accY[0][i], A1 = accY[1][i], A2 = accY[2][i];
        const float W0 = __shfl_xor(A0, 8, 64);
        const float W1 = __shfl_xor(A1, 8, 64);
        const float W2 = __shfl_xor(A2, 8, 64);
        const float q0 = A0 + (h1*W2 - h2*W1) + h0*sd;
        const float q1 = A1 + (h2*W0 - h0*W2) + h1*sd;
        const float q2 = A2 + (h0*W1 - h1*W0) + h2*sd;
        nd[0] += accX[0][i] + h0*q0;  nd[1] += accX[1][i] + h0*q1;  nd[2] += accX[2][i] + h0*q2;
        nd[3] += accX[3][i] + h1*q0;  nd[4] += accX[4][i] + h1*q1;  nd[5] += accX[5][i] + h1*q2;
        nd[6] += accX[6][i] + h2*q0;  nd[7] += accX[7][i] + h2*q1;  nd[8] += accX[8][i] + h2*q2;
      }
    }

    #pragma unroll
    for (int k = 0; k < 9; k++) {
      nd[k] += __shfl_xor(nd[k], 16, 64);
      nd[k] += __shfl_xor(nd[k], 32, 64);
    }
    if (lane < 8) {
      float* o = outD + (size_t)n*72 + lane*9;
      #pragma unroll
      for (int k = 0; k < 9; k++) o[k] = 0.1f*nd[k];
    }
  }
}

// ======================= scalar fallback (insurance only; runs if ws too small) =======================
__global__ __launch_bounds__(256) void fallback_all(
    const float* __restrict__ r_ij, const float* __restrict__ x_a,
    const float* __restrict__ x_v,  const float* __restrict__ x_d,
    const float* __restrict__ P000, const float* __restrict__ P110, const float* __restrict__ P220,
    const float* __restrict__ P011, const float* __restrict__ P101, const float* __restrict__ P121,
    const float* __restrict__ P211, const float* __restrict__ P111,
    const float* __restrict__ P022, const float* __restrict__ P202, const float* __restrict__ P112,
    const float* __restrict__ P222, const float* __restrict__ P212,
    const int* __restrict__ src, const int* __restrict__ dst, int E,
    float* __restrict__ outA, float* __restrict__ outV, float* __restrict__ outD)
{
  const int e = blockIdx.x*256 + threadIdx.x;
  if (e >= E) return;
  Geom g;
  if (!geom_of(r_ij, e, g)) return;
  const int nj = dst[e], ni = src[e];
  const float* xa = x_a + (size_t)nj*32;
  const float* xv = x_v + (size_t)nj*48;
  const float* xd = x_d + (size_t)nj*72;
  float V0[16],V1[16],V2[16],s1[16],T0[8],T1[8],T2[8],s2[8];
  for (int b = 0; b < 16; b++) {
    V0[b]=xv[3*b]; V1[b]=xv[3*b+1]; V2[b]=xv[3*b+2];
    s1[b]=g.h0*V0[b]+g.h1*V1[b]+g.h2*V2[b];
  }
  for (int b = 0; b < 8; b++) {
    const float* m = xd + 9*b;
    T0[b]=g.h0*m[0]+g.h1*m[3]+g.h2*m[6];
    T1[b]=g.h0*m[1]+g.h1*m[4]+g.h2*m[7];
    T2[b]=g.h0*m[2]+g.h1*m[5]+g.h2*m[8];
    s2[b]=g.h0*T0[b]+g.h1*T1[b]+g.h2*T2[b];
  }
  for (int a = 0; a < 32; a++) {
    float acc = 0;
    for (int l = 0; l < 8; l++) {
      float u = 0;
      for (int b = 0; b < 32; b++) u += P000[(a*8+l)*32+b]*xa[b];
      for (int b = 0; b < 16; b++) u += P110[(a*8+l)*16+b]*s1[b];
      for (int b = 0; b < 8;  b++) u += P220[(a*8+l)*8+b]*s2[b];
      acc += g.enc[l]*u;
    }
    atomicAdd(outA + (size_t)ni*32 + a, 0.1f*acc);
  }
  for (int v = 0; v < 16; v++) {
    float sv=0,A0=0,A1=0,A2=0,W0=0,W1=0,W2=0;
    for (int l = 0; l < 8; l++) {
      const float el = g.enc[l];
      float u=0;
      for (int b=0;b<32;b++) u += P101[(v*8+l)*32+b]*xa[b];
      for (int b=0;b<16;b++) u += P211[(v*8+l)*16+b]*s1[b];
      sv += el*u;
      float a0=0,a1=0,a2=0,w0=0,w1=0,w2=0;
      for (int b=0;b<16;b++){float p=P011[(v*8+l)*16+b]; a0+=p*V0[b];a1+=p*V1[b];a2+=p*V2[b];}
      for (int b=0;b<8;b++){float p=P121[(v*8+l)*8+b]; a0+=p*T0[b];a1+=p*T1[b];a2+=p*T2[b];}
      for (int b=0;b<16;b++){float p=P111[(v*8+l)*16+b]; w0+=p*V0[b];w1+=p*V1[b];w2+=p*V2[b];}
      A0+=el*a0;A1+=el*a1;A2+=el*a2;W0+=el*w0;W1+=el*w1;W2+=el*w2;
    }
    float* o = outV + (size_t)ni*48 + v*3;
    atomicAdd(o+0, 0.1f*(A0 + (g.h1*W2-g.h2*W1) + g.h0*sv));
    atomicAdd(o+1, 0.1f*(A1 + (g.h2*W0-g.h0*W2) + g.h1*sv));
    atomicAdd(o+2, 0.1f*(A2 + (g.h0*W1-g.h1*W0) + g.h2*sv));
  }
  const float hh[3]={g.h0,g.h1,g.h2};
  for (int d = 0; d < 8; d++) {
    float sd=0,A0=0,A1=0,A2=0,W0=0,W1=0,W2=0;
    float w[8]={0,0,0,0,0,0,0,0};
    for (int l = 0; l < 8; l++) {
      const float el = g.enc[l];
      float u=0;
      for (int b=0;b<32;b++) u += P202[(d*8+l)*32+b]*xa[b];
      sd += el*u;
      float a0=0,a1=0,a2=0,w0=0,w1=0,w2=0;
      for (int b=0;b<16;b++){float p=P112[(d*8+l)*16+b]; a0+=p*V0[b];a1+=p*V1[b];a2+=p*V2[b];}
      for (int b=0;b<8;b++){float p=P222[(d*8+l)*8+b]; a0+=p*T0[b];a1+=p*T1[b];a2+=p*T2[b];}
      for (int b=0;b<16;b++){float p=P212[(d*8+l)*16+b]; w0+=p*V0[b];w1+=p*V1[b];w2+=p*V2[b];}
      A0+=el*a0;A1+=el*a1;A2+=el*a2;W0+=el*w0;W1+=el*w1;W2+=el*w2;
      for (int b=0;b<8;b++) w[b]+=el*P022[(d*8+l)*8+b];
    }
    const float q[3] = { A0+(g.h1*W2-g.h2*W1)+g.h0*sd,
                         A1+(g.h2*W0-g.h0*W2)+g.h1*sd,
                         A2+(g.h0*W1-g.h1*W0)+g.h2*sd };
    float* o = outD + (size_t)ni*72 + d*9;
    for (int ii = 0; ii < 3; ii++)
      for (int jj = 0; jj < 3; jj++) {
        float acc = 0;
        for (int b = 0; b < 8; b++) acc += w[b]*xd[9*b + ii*3 + jj];
        atomicAdd(o + ii*3 + jj, 0.1f*(acc + hh[ii]*q[jj]));
      }
  }
}

extern "C" void kernel_launch(void* const* d_in, const int* in_sizes, int n_in,
                              void* d_out, int out_size, void* d_ws, size_t ws_size,
                              hipStream_t stream) {
  const float* r_ij = (const float*)d_in[0];
  const float* x_a  = (const float*)d_in[1];
  const float* x_v  = (const float*)d_in[2];
  const float* x_d  = (const float*)d_in[3];
  const float* P000 = (const float*)d_in[4];
  const float* P110 = (const float*)d_in[5];
  const float* P220 = (const float*)d_in[6];
  const float* P011 = (const float*)d_in[7];
  const float* P101 = (const float*)d_in[8];
  const float* P121 = (const float*)d_in[9];
  const float* P211 = (const float*)d_in[10];
  const float* P111 = (const float*)d_in[11];
  const float* P022 = (const float*)d_in[12];
  const float* P202 = (const float*)d_in[13];
  const float* P112 = (const float*)d_in[14];
  const float* P222 = (const float*)d_in[15];
  const float* P212 = (const float*)d_in[16];
  const int* src = (const int*)d_in[17];
  const int* dst = (const int*)d_in[18];

  const int E  = in_sizes[17];
  const int Nn = in_sizes[1] / 32;
  float* out  = (float*)d_out;
  float* outA = out;
  float* outV = out + (size_t)Nn*32;
  float* outD = out + (size_t)Nn*80;

  const size_t need = 4ull * (2ull*(size_t)Nn + 1 + (size_t)E);
  if (ws_size >= need) {
    int* hist    = (int*)d_ws;
    int* row_ptr = hist + Nn;
    int* sorted  = row_ptr + Nn + 1;
    hipMemsetAsync(hist, 0, (size_t)Nn*sizeof(int), stream);
    hist_k   <<<(E + 255)/256, 256, 0, stream>>>(r_ij, src, E, hist);
    scan_k   <<<1, 256, 0, stream>>>(hist, Nn, row_ptr);
    scatter_k<<<(E + 255)/256, 256, 0, stream>>>(r_ij, src, E, hist, sorted);

    const int ngrp = (Nn + 3) / 4;
    const int gS = min(1024, ngrp);   // 4 blocks/CU (38 KB LDS)
    const int gV = min(768,  ngrp);   // 3 blocks/CU (46 KB LDS)
    const int gD = min(768,  ngrp);   // 3 blocks/CU (47 KB LDS)
    msgS_csr<<<gS, 256, 0, stream>>>(r_ij, x_a, x_v, x_d,
        P000, P110, P220, dst, row_ptr, sorted, Nn, outA);
    msgV_csr<<<gV, 256, 0, stream>>>(r_ij, x_a, x_v, x_d,
        P011, P101, P121, P211, P111, dst, row_ptr, sorted, Nn, outV);
    msgD_csr<<<gD, 256, 0, stream>>>(r_ij, x_a, x_v, x_d,
        P022, P202, P112, P222, P212, dst, row_ptr, sorted, Nn, outD);
  } else {
    hipMemsetAsync(d_out, 0, (size_t)out_size * sizeof(float), stream);
    fallback_all<<<(E + 255)/256, 256, 0, stream>>>(r_ij, x_a, x_v, x_d,
        P000, P110, P220, P011, P101, P121, P211, P111,
        P022, P202, P112, P222, P212, src, dst, E, outA, outV, outD);
  }
}

// Round 10
// 187.165 us; speedup vs baseline: 13.8282x; 1.5502x over previous
//
#include <hip/hip_runtime.h>

#define PI_F 3.14159265358979323846f

typedef _Float16 h8 __attribute__((ext_vector_type(8)));
typedef _Float16 h2v __attribute__((ext_vector_type(2)));
typedef float f4 __attribute__((ext_vector_type(4)));
typedef unsigned int u32;

struct Geom { float enc[8]; float h0, h1, h2; };

__device__ __forceinline__ bool geom_of(const float* __restrict__ r, int e, Geom& g) {
  const float rx = r[3*e], ry = r[3*e+1], rz = r[3*e+2];
  const float xsq = (rx*rx + ry*ry + rz*rz) * (1.0f/2.5f);
  const float cut = 1.0f - xsq;
  if (cut <= 0.0f) return false;
  const float c1 = cosf(PI_F * sqrtf(xsq));
  g.enc[0] = cut; g.enc[1] = c1*cut;
  float cp = 1.0f, cc = c1;
  #pragma unroll
  for (int n = 2; n < 8; n++) { float cn = 2.0f*c1*cc - cp; cp = cc; cc = cn; g.enc[n] = cn*cut; }
  const float s = 7.0f/2.5f;
  const float yx = rx*s, yy = ry*s, yz = rz*s;
  const float inv = rsqrtf(1.0f + yx*yx + yy*yy + yz*yz);
  g.h0 = yx*inv; g.h1 = yy*inv; g.h2 = yz*inv;
  return true;
}

__device__ __forceinline__ u32 pk2(float a, float b) {
  union { h2v h; u32 u; } r;
  r.h.x = (_Float16)a; r.h.y = (_Float16)b;
  return r.u;
}

__device__ __forceinline__ h8 mul_enc(uint4 c, u32 e) {
  union { uint4 u; h2v p[4]; } C; C.u = c;
  union { u32 u; h2v h; } E; E.u = e;
  union { h2v p[4]; h8 v; } R;
  #pragma unroll
  for (int i = 0; i < 4; i++) R.p[i] = C.p[i] * E.h;
  return R.v;
}

__device__ __forceinline__ h8 as_h8(uint4 c) { union { uint4 u; h8 v; } r; r.u = c; return r.v; }

__device__ __forceinline__ void wave_lds_fence() {
  asm volatile("s_waitcnt lgkmcnt(0)" ::: "memory");
  __builtin_amdgcn_sched_barrier(0);
}

// ======================= CSR build =======================
__global__ __launch_bounds__(256) void hist_k(const float* __restrict__ r, const int* __restrict__ src,
                                              int E, int* __restrict__ hist) {
  int e = blockIdx.x * 256 + threadIdx.x;
  if (e >= E) return;
  float rx = r[3*e], ry = r[3*e+1], rz = r[3*e+2];
  float xsq = (rx*rx + ry*ry + rz*rz) * (1.0f/2.5f);
  if (xsq < 1.0f) atomicAdd(&hist[src[e]], 1);
}

__global__ __launch_bounds__(256) void scan_k(int* __restrict__ hist, int Nn, int* __restrict__ row_ptr) {
  __shared__ int part[256];
  const int t = threadIdx.x;
  const int chunk = (Nn + 255) / 256;
  const int i0 = t * chunk;
  int s = 0;
  for (int j = 0; j < chunk; j++) { int i = i0 + j; if (i < Nn) s += hist[i]; }
  part[t] = s;
  __syncthreads();
  for (int off = 1; off < 256; off <<= 1) {
    int v = (t >= off) ? part[t - off] : 0;
    __syncthreads();
    part[t] += v;
    __syncthreads();
  }
  int run = part[t] - s;
  for (int j = 0; j < chunk; j++) {
    int i = i0 + j;
    if (i < Nn) { int h = hist[i]; row_ptr[i] = run; hist[i] = run; run += h; }
  }
  if (t == 255) row_ptr[Nn] = part[255];
}

__global__ __launch_bounds__(256) void scatter_k(const float* __restrict__ r, const int* __restrict__ src,
                                                 int E, int* __restrict__ cur, int* __restrict__ sorted) {
  int e = blockIdx.x * 256 + threadIdx.x;
  if (e >= E) return;
  float rx = r[3*e], ry = r[3*e+1], rz = r[3*e+2];
  float xsq = (rx*rx + ry*ry + rz*rz) * (1.0f/2.5f);
  if (xsq < 1.0f) {
    int p = atomicAdd(&cur[src[e]], 1);
    sorted[p] = e;
  }
}

// ======================= merged rank-specialized persistent kernel =======================
// blocks [0,gS): psi_a ; [gS,gS+gV): psi_v ; rest: psi_d. 47KB LDS -> 3 blocks/CU.
__global__ __launch_bounds__(256, 3) void msgAll_k(
    const float* __restrict__ r_ij, const float* __restrict__ x_a,
    const float* __restrict__ x_v,  const float* __restrict__ x_d,
    const float* __restrict__ P000, const float* __restrict__ P110, const float* __restrict__ P220,
    const float* __restrict__ P011, const float* __restrict__ P101, const float* __restrict__ P121,
    const float* __restrict__ P211, const float* __restrict__ P111,
    const float* __restrict__ P022, const float* __restrict__ P202, const float* __restrict__ P112,
    const float* __restrict__ P222, const float* __restrict__ P212,
    const int* __restrict__ dst,
    const int* __restrict__ row_ptr, const int* __restrict__ sorted, int Nn,
    int gS, int gV,
    float* __restrict__ outA, float* __restrict__ outV, float* __restrict__ outD)
{
  __shared__ __align__(16) u32 smem[11776];
  const int rank = (blockIdx.x < (u32)gS) ? 0 : ((blockIdx.x < (u32)(gS+gV)) ? 1 : 2);

  // ---- stage this rank's weight fragments ----
  if (rank == 0) {
    for (int i = threadIdx.x; i < 7168; i += 256) {
      const int p = i & 3, ln = (i >> 2) & 63, rest = i >> 8;
      const int step = rest % 14, tile = rest / 14;
      const int k = step*32 + (ln >> 4)*8 + 2*p;
      const int n = tile*16 + (ln & 15);
      const int l = k / 56, b = k - l*56;
      const int base = n*8 + l;
      float w0, w1;
      if (b < 32)      { w0 = P000[base*32 + b];      w1 = P000[base*32 + b + 1]; }
      else if (b < 48) { w0 = P110[base*16 + (b-32)]; w1 = P110[base*16 + (b-31)]; }
      else             { w0 = P220[base*8  + (b-48)]; w1 = P220[base*8  + (b-47)]; }
      smem[i] = pk2(w0, w1);
    }
  } else if (rank == 1) {
    for (int i = threadIdx.x; i < 6144; i += 256) {
      const int p = i & 3, ln = (i >> 2) & 63;
      const int n = ln & 15, kgq = ln >> 4;
      float w0 = 0.0f, w1 = 0.0f;
      if (i < 3072) {
        const int step = i >> 8;
        const int k = step*32 + kgq*8 + 2*p;
        const int l = k / 48, ch = k - l*48;
        const int base = n*8 + l;
        if (ch < 32) { w0 = P101[base*32 + ch];      w1 = P101[base*32 + ch + 1]; }
        else         { w0 = P211[base*16 + (ch-32)]; w1 = P211[base*16 + (ch-31)]; }
      } else {
        const int iy = i - 3072;
        const int rest = iy >> 8;
        const int step = rest % 6, tile = rest / 6;
        const int k = step*32 + kgq*8 + 2*p;
        const int l = k / 24, ch = k - l*24;
        const int base = n*8 + l;
        if (tile == 0) {
          if (ch < 16) { w0 = P011[base*16 + ch];      w1 = P011[base*16 + ch + 1]; }
          else         { w0 = P121[base*8 + (ch-16)];  w1 = P121[base*8 + (ch-15)]; }
        } else {
          if (ch < 16) { w0 = P111[base*16 + ch];      w1 = P111[base*16 + ch + 1]; }
        }
      }
      smem[i] = pk2(w0, w1);
    }
  } else {
    for (int i = threadIdx.x; i < 4096; i += 256) {
      const int p = i & 3, ln = (i >> 2) & 63;
      const int n16 = ln & 15, kgq = ln >> 4;
      float w0 = 0.0f, w1 = 0.0f;
      if (i < 2048) {
        const int step = i >> 8;
        const int k = step*32 + kgq*8 + 2*p;
        const int l = k >> 5, ch = k & 31;
        if (n16 < 8) { const int b = (n16*8 + l)*32 + ch; w0 = P202[b]; w1 = P202[b+1]; }
      } else if (i < 3584) {
        const int step = (i - 2048) >> 8;
        const int k = step*32 + kgq*8 + 2*p;
        const int l = k / 24, ch = k - l*24;
        if (n16 < 8) {
          if (ch < 16) { const int b = (n16*8 + l)*16 + ch;      w0 = P112[b]; w1 = P112[b+1]; }
          else         { const int b = (n16*8 + l)*8 + (ch-16);  w0 = P222[b]; w1 = P222[b+1]; }
        } else {
          const int d_ = n16 - 8;
          if (ch < 16) { const int b = (d_*8 + l)*16 + ch;       w0 = P212[b]; w1 = P212[b+1]; }
        }
      } else {
        const int step = (i - 3584) >> 8;
        const int k = step*32 + kgq*8 + 2*p;
        const int l = k >> 3, bb = k & 7;
        if (n16 < 8) { const int b = (n16*8 + l)*8 + bb; w0 = P022[b]; w1 = P022[b+1]; }
      }
      smem[i] = pk2(w0, w1);
    }
  }
  __syncthreads();

  const int wv = threadIdx.x >> 6;
  const int lane = threadIdx.x & 63;
  const int et = lane >> 2, part = lane & 3;
  const int row = lane & 15, kg = lane >> 4;

  int bid, nb;
  if (rank == 0)      { bid = blockIdx.x;          nb = gS; }
  else if (rank == 1) { bid = blockIdx.x - gS;     nb = gV; }
  else                { bid = blockIdx.x - gS - gV; nb = (int)gridDim.x - gS - gV; }
  const int W = nb * 4;

  // ================= rank 0: psi_a =================
  if (rank == 0) {
    u32* sc_ = smem + 7168 + wv*448;
    u32* se_ = smem + 8960 + wv*144;
    for (int n = bid*4 + wv; n < Nn; n += W) {
      const int beg = row_ptr[n], end = row_ptr[n+1];
      const int nch = (end - beg + 15) >> 4;
      f4 acc0 = {0,0,0,0}, acc1 = {0,0,0,0};

      for (int ch = 0; ch < nch; ch++) {
        const int ei = beg + ch*16 + et;
        const int e = (ei < end) ? sorted[ei] : -1;
        Geom g = {};
        const bool ok = (e >= 0) && geom_of(r_ij, e, g);
        float4 a0={0,0,0,0}, a1={0,0,0,0}, v0={0,0,0,0}, v1={0,0,0,0}, v2={0,0,0,0};
        float dd[18] = {0,0,0,0,0,0,0,0,0,0,0,0,0,0,0,0,0,0};
        if (ok) {
          const int nj = dst[e];
          const float4* xa4 = (const float4*)(x_a + (size_t)nj*32);
          a0 = xa4[2*part]; a1 = xa4[2*part+1];
          const float4* xv4 = (const float4*)(x_v + (size_t)nj*48);
          v0 = xv4[3*part]; v1 = xv4[3*part+1]; v2 = xv4[3*part+2];
          const float2* xd2 = (const float2*)(x_d + (size_t)nj*72) + 9*part;
          #pragma unroll
          for (int q = 0; q < 9; q++) { float2 f = xd2[q]; dd[2*q] = f.x; dd[2*q+1] = f.y; }
        }
        const float h0 = g.h0, h1 = g.h1, h2 = g.h2;
        // xa (4 pk2)
        sc_[et*28 + 4*part + 0] = pk2(a0.x, a0.y);
        sc_[et*28 + 4*part + 1] = pk2(a0.z, a0.w);
        sc_[et*28 + 4*part + 2] = pk2(a1.x, a1.y);
        sc_[et*28 + 4*part + 3] = pk2(a1.z, a1.w);
        // s1 (2 pk2)
        sc_[et*28 + 16 + 2*part]     = pk2(h0*v0.x + h1*v0.y + h2*v0.z, h0*v0.w + h1*v1.x + h2*v1.y);
        sc_[et*28 + 16 + 2*part + 1] = pk2(h0*v1.z + h1*v1.w + h2*v2.x, h0*v2.y + h1*v2.z + h2*v2.w);
        // s2 rows 2p,2p+1 (1 pk2)
        {
          float t0 = h0*dd[0] + h1*dd[3] + h2*dd[6];
          float t1 = h0*dd[1] + h1*dd[4] + h2*dd[7];
          float t2 = h0*dd[2] + h1*dd[5] + h2*dd[8];
          float sa = h0*t0 + h1*t1 + h2*t2;
          float u0 = h0*dd[9]  + h1*dd[12] + h2*dd[15];
          float u1 = h0*dd[10] + h1*dd[13] + h2*dd[16];
          float u2 = h0*dd[11] + h1*dd[14] + h2*dd[17];
          float sb = h0*u0 + h1*u1 + h2*u2;
          sc_[et*28 + 24 + part] = pk2(sa, sb);
        }
        // enc (2 pk2, static-index select)
        {
          float eA = part==0 ? g.enc[0] : (part==1 ? g.enc[2] : (part==2 ? g.enc[4] : g.enc[6]));
          float eB = part==0 ? g.enc[1] : (part==1 ? g.enc[3] : (part==2 ? g.enc[5] : g.enc[7]));
          se_[et*9 + 2*part]     = pk2(eA, eA);
          se_[et*9 + 2*part + 1] = pk2(eB, eB);
        }
        wave_lds_fence();
        #pragma unroll
        for (int s = 0; s < 14; s++) {
          const int m = 4*s + kg;
          const int l = m / 7;
          const int j = m - l*7;
          const uint4 ca = *(const uint4*)&sc_[row*28 + j*4];
          const h8 af = mul_enc(ca, se_[row*9 + l]);
          const h8 b0 = as_h8(*(const uint4*)&smem[(s*64 + lane)*4]);
          const h8 b1 = as_h8(*(const uint4*)&smem[((14 + s)*64 + lane)*4]);
          acc0 = __builtin_amdgcn_mfma_f32_16x16x32_f16(af, b0, acc0, 0, 0, 0);
          acc1 = __builtin_amdgcn_mfma_f32_16x16x32_f16(af, b1, acc1, 0, 0, 0);
        }
      }

      float o0 = (acc0[0]+acc0[1])+(acc0[2]+acc0[3]);
      float o1 = (acc1[0]+acc1[1])+(acc1[2]+acc1[3]);
      o0 += __shfl_xor(o0, 16, 64); o0 += __shfl_xor(o0, 32, 64);
      o1 += __shfl_xor(o1, 16, 64); o1 += __shfl_xor(o1, 32, 64);
      if (lane < 16) {
        outA[(size_t)n*32 + lane]      = 0.1f*o0;
        outA[(size_t)n*32 + 16 + lane] = 0.1f*o1;
      }
    }
  }
  // ================= rank 1: psi_v =================
  else if (rank == 1) {
    u32* sx_ = smem + 6144 + wv*448;
    u32* sy_ = smem + 7936 + wv*704;
    u32* se_ = smem + 10752 + wv*144;
    float* sh_ = (float*)(smem + 11328) + wv*48;
    for (int n = bid*4 + wv; n < Nn; n += W) {
      const int beg = row_ptr[n], end = row_ptr[n+1];
      const int nch = (end - beg + 15) >> 4;
      float nv0 = 0.f, nv1 = 0.f, nv2 = 0.f;

      for (int ch = 0; ch < nch; ch++) {
        const int ei = beg + ch*16 + et;
        const int e = (ei < end) ? sorted[ei] : -1;
        Geom g = {};
        const bool ok = (e >= 0) && geom_of(r_ij, e, g);
        float4 a0={0,0,0,0}, a1={0,0,0,0}, v0={0,0,0,0}, v1={0,0,0,0}, v2={0,0,0,0};
        float dd[18] = {0,0,0,0,0,0,0,0,0,0,0,0,0,0,0,0,0,0};
        if (ok) {
          const int nj = dst[e];
          const float4* xa4 = (const float4*)(x_a + (size_t)nj*32);
          a0 = xa4[2*part]; a1 = xa4[2*part+1];
          const float4* xv4 = (const float4*)(x_v + (size_t)nj*48);
          v0 = xv4[3*part]; v1 = xv4[3*part+1]; v2 = xv4[3*part+2];
          const float2* xd2 = (const float2*)(x_d + (size_t)nj*72) + 9*part;
          #pragma unroll
          for (int q = 0; q < 9; q++) { float2 f = xd2[q]; dd[2*q] = f.x; dd[2*q+1] = f.y; }
        }
        const float h0 = g.h0, h1 = g.h1, h2 = g.h2;
        // xa
        sx_[et*28 + 4*part + 0] = pk2(a0.x, a0.y);
        sx_[et*28 + 4*part + 1] = pk2(a0.z, a0.w);
        sx_[et*28 + 4*part + 2] = pk2(a1.x, a1.y);
        sx_[et*28 + 4*part + 3] = pk2(a1.z, a1.w);
        // s1
        sx_[et*28 + 16 + 2*part]     = pk2(h0*v0.x + h1*v0.y + h2*v0.z, h0*v0.w + h1*v1.x + h2*v1.y);
        sx_[et*28 + 16 + 2*part + 1] = pk2(h0*v1.z + h1*v1.w + h2*v2.x, h0*v2.y + h1*v2.z + h2*v2.w);
        // Y V-part: vv[] = {v0.xyzw v1.xyzw v2.xyzw}; c unrolled static
        sy_[et*44 + 0*12 + 2*part]     = pk2(v0.x, v0.w);
        sy_[et*44 + 0*12 + 2*part + 1] = pk2(v1.z, v2.y);
        sy_[et*44 + 1*12 + 2*part]     = pk2(v0.y, v1.x);
        sy_[et*44 + 1*12 + 2*part + 1] = pk2(v1.w, v2.z);
        sy_[et*44 + 2*12 + 2*part]     = pk2(v0.z, v1.y);
        sy_[et*44 + 2*12 + 2*part + 1] = pk2(v2.x, v2.w);
        // Y T-part
        #pragma unroll
        for (int c = 0; c < 3; c++) {
          float a = h0*dd[c]   + h1*dd[3+c]  + h2*dd[6+c];
          float b = h0*dd[9+c] + h1*dd[12+c] + h2*dd[15+c];
          sy_[et*44 + c*12 + 8 + part] = pk2(a, b);
        }
        // enc
        {
          float eA = part==0 ? g.enc[0] : (part==1 ? g.enc[2] : (part==2 ? g.enc[4] : g.enc[6]));
          float eB = part==0 ? g.enc[1] : (part==1 ? g.enc[3] : (part==2 ? g.enc[5] : g.enc[7]));
          se_[et*9 + 2*part]     = pk2(eA, eA);
          se_[et*9 + 2*part + 1] = pk2(eB, eB);
        }
        if (part < 3) {
          float hv = part==0 ? h0 : (part==1 ? h1 : h2);
          sh_[et*3 + part] = hv;
        }
        wave_lds_fence();

        f4 accS = {0,0,0,0};
        #pragma unroll
        for (int s = 0; s < 12; s++) {
          const int m = 4*s + kg;
          const int l = m / 6;
          const int j = m - l*6;
          const uint4 ca = *(const uint4*)&sx_[row*28 + j*4];
          const h8 af = mul_enc(ca, se_[row*9 + l]);
          const h8 bf = as_h8(*(const uint4*)&smem[(s*64 + lane)*4]);
          accS = __builtin_amdgcn_mfma_f32_16x16x32_f16(af, bf, accS, 0, 0, 0);
        }
        f4 accA[3], accW[3];
        #pragma unroll
        for (int c = 0; c < 3; c++) { accA[c] = f4{0,0,0,0}; accW[c] = f4{0,0,0,0}; }
        #pragma unroll
        for (int c = 0; c < 3; c++) {
          #pragma unroll
          for (int s = 0; s < 6; s++) {
            const int m = 4*s + kg;
            const int l = m / 3;
            const int j = m - l*3;
            const uint4 ca = *(const uint4*)&sy_[row*44 + c*12 + j*4];
            const h8 af = mul_enc(ca, se_[row*9 + l]);
            const h8 bA = as_h8(*(const uint4*)&smem[3072 + (s*64 + lane)*4]);
            const h8 bW = as_h8(*(const uint4*)&smem[3072 + ((6 + s)*64 + lane)*4]);
            accA[c] = __builtin_amdgcn_mfma_f32_16x16x32_f16(af, bA, accA[c], 0, 0, 0);
            accW[c] = __builtin_amdgcn_mfma_f32_16x16x32_f16(af, bW, accW[c], 0, 0, 0);
          }
        }
        #pragma unroll
        for (int i = 0; i < 4; i++) {
          const int r = kg*4 + i;
          const float rh0 = sh_[r*3], rh1 = sh_[r*3+1], rh2 = sh_[r*3+2];
          const float sv = accS[i];
          const float A0 = accA[0][i], A1 = accA[1][i], A2 = accA[2][i];
          const float W0 = accW[0][i], W1 = accW[1][i], W2 = accW[2][i];
          nv0 += A0 + (rh1*W2 - rh2*W1) + rh0*sv;
          nv1 += A1 + (rh2*W0 - rh0*W2) + rh1*sv;
          nv2 += A2 + (rh0*W1 - rh1*W0) + rh2*sv;
        }
      }

      nv0 += __shfl_xor(nv0, 16, 64); nv0 += __shfl_xor(nv0, 32, 64);
      nv1 += __shfl_xor(nv1, 16, 64); nv1 += __shfl_xor(nv1, 32, 64);
      nv2 += __shfl_xor(nv2, 16, 64); nv2 += __shfl_xor(nv2, 32, 64);
      if (lane < 16) {
        float* o = outV + (size_t)n*48 + lane*3;
        o[0] = 0.1f*nv0; o[1] = 0.1f*nv1; o[2] = 0.1f*nv2;
      }
    }
  }
  // ================= rank 2: psi_d =================
  else {
    u32* sa_ = smem + 4096 + wv*320;
    u32* sy_ = smem + 5376 + wv*704;
    u32* sxp = smem + 8192 + wv*704;
    u32* se_ = smem + 11008 + wv*144;
    float* sh_ = (float*)(smem + 11584) + wv*48;
    for (int n = bid*4 + wv; n < Nn; n += W) {
      const int beg = row_ptr[n], end = row_ptr[n+1];
      const int nch = (end - beg + 15) >> 4;
      float nd[9] = {0,0,0,0,0,0,0,0,0};

      for (int ch = 0; ch < nch; ch++) {
        const int ei = beg + ch*16 + et;
        const int e = (ei < end) ? sorted[ei] : -1;
        Geom g = {};
        const bool ok = (e >= 0) && geom_of(r_ij, e, g);
        float4 a0={0,0,0,0}, a1={0,0,0,0}, v0={0,0,0,0}, v1={0,0,0,0}, v2={0,0,0,0};
        float dd[18] = {0,0,0,0,0,0,0,0,0,0,0,0,0,0,0,0,0,0};
        if (ok) {
          const int nj = dst[e];
          const float4* xa4 = (const float4*)(x_a + (size_t)nj*32);
          a0 = xa4[2*part]; a1 = xa4[2*part+1];
          const float4* xv4 = (const float4*)(x_v + (size_t)nj*48);
          v0 = xv4[3*part]; v1 = xv4[3*part+1]; v2 = xv4[3*part+2];
          const float2* xd2 = (const float2*)(x_d + (size_t)nj*72) + 9*part;
          #pragma unroll
          for (int q = 0; q < 9; q++) { float2 f = xd2[q]; dd[2*q] = f.x; dd[2*q+1] = f.y; }
        }
        const float h0 = g.h0, h1 = g.h1, h2 = g.h2;
        // xa
        sa_[et*20 + 4*part + 0] = pk2(a0.x, a0.y);
        sa_[et*20 + 4*part + 1] = pk2(a0.z, a0.w);
        sa_[et*20 + 4*part + 2] = pk2(a1.x, a1.y);
        sa_[et*20 + 4*part + 3] = pk2(a1.z, a1.w);
        // Y V-part
        sy_[et*44 + 0*12 + 2*part]     = pk2(v0.x, v0.w);
        sy_[et*44 + 0*12 + 2*part + 1] = pk2(v1.z, v2.y);
        sy_[et*44 + 1*12 + 2*part]     = pk2(v0.y, v1.x);
        sy_[et*44 + 1*12 + 2*part + 1] = pk2(v1.w, v2.z);
        sy_[et*44 + 2*12 + 2*part]     = pk2(v0.z, v1.y);
        sy_[et*44 + 2*12 + 2*part + 1] = pk2(v2.x, v2.w);
        // Y T-part
        #pragma unroll
        for (int c = 0; c < 3; c++) {
          float a = h0*dd[c]   + h1*dd[3+c]  + h2*dd[6+c];
          float b = h0*dd[9+c] + h1*dd[12+c] + h2*dd[15+c];
          sy_[et*44 + c*12 + 8 + part] = pk2(a, b);
        }
        // X: rows 2p,2p+1, 9 pk2
        #pragma unroll
        for (int ij = 0; ij < 9; ij++)
          sxp[et*44 + ij*4 + part] = pk2(dd[ij], dd[9+ij]);
        // enc
        {
          float eA = part==0 ? g.enc[0] : (part==1 ? g.enc[2] : (part==2 ? g.enc[4] : g.enc[6]));
          float eB = part==0 ? g.enc[1] : (part==1 ? g.enc[3] : (part==2 ? g.enc[5] : g.enc[7]));
          se_[et*9 + 2*part]     = pk2(eA, eA);
          se_[et*9 + 2*part + 1] = pk2(eB, eB);
        }
        if (part < 3) {
          float hv = part==0 ? h0 : (part==1 ? h1 : h2);
          sh_[et*3 + part] = hv;
        }
        wave_lds_fence();

        f4 accSd = {0,0,0,0};
        #pragma unroll
        for (int s = 0; s < 8; s++) {
          const int m = 4*s + kg;
          const int l = m >> 2, j = m & 3;
          const uint4 ca = *(const uint4*)&sa_[row*20 + j*4];
          const h8 af = mul_enc(ca, se_[row*9 + l]);
          const h8 bf = as_h8(*(const uint4*)&smem[(s*64 + lane)*4]);
          accSd = __builtin_amdgcn_mfma_f32_16x16x32_f16(af, bf, accSd, 0, 0, 0);
        }
        f4 accY[3];
        #pragma unroll
        for (int c = 0; c < 3; c++) accY[c] = f4{0,0,0,0};
        #pragma unroll
        for (int c = 0; c < 3; c++) {
          #pragma unroll
          for (int s = 0; s < 6; s++) {
            const int m = 4*s + kg;
            const int l = m / 3;
            const int j = m - l*3;
            const uint4 ca = *(const uint4*)&sy_[row*44 + c*12 + j*4];
            const h8 af = mul_enc(ca, se_[row*9 + l]);
            const h8 bf = as_h8(*(const uint4*)&smem[2048 + (s*64 + lane)*4]);
            accY[c] = __builtin_amdgcn_mfma_f32_16x16x32_f16(af, bf, accY[c], 0, 0, 0);
          }
        }
        f4 accX[9];
        #pragma unroll
        for (int ij = 0; ij < 9; ij++) accX[ij] = f4{0,0,0,0};
        #pragma unroll
        for (int ij = 0; ij < 9; ij++) {
          const uint4 ca = *(const uint4*)&sxp[row*44 + ij*4];
          #pragma unroll
          for (int s = 0; s < 2; s++) {
            const h8 af = mul_enc(ca, se_[row*9 + 4*s + kg]);
            const h8 bf = as_h8(*(const uint4*)&smem[3584 + (s*64 + lane)*4]);
            accX[ij] = __builtin_amdgcn_mfma_f32_16x16x32_f16(af, bf, accX[ij], 0, 0, 0);
          }
        }
        #pragma unroll
        for (int i = 0; i < 4; i++) {
          const int r = kg*4 + i;
          const float rh0 = sh_[r*3], rh1 = sh_[r*3+1], rh2 = sh_[r*3+2];
          const float sd = accSd[i];
          const float A0 = accY[0][i], A1 = accY[1][i], A2 = accY[2][i];
          const float W0 = __shfl_xor(A0, 8, 64);
          const float W1 = __shfl_xor(A1, 8, 64);
          const float W2 = __shfl_xor(A2, 8, 64);
          const float q0 = A0 + (rh1*W2 - rh2*W1) + rh0*sd;
          const float q1 = A1 + (rh2*W0 - rh0*W2) + rh1*sd;
          const float q2 = A2 + (rh0*W1 - rh1*W0) + rh2*sd;
          nd[0] += accX[0][i] + rh0*q0;  nd[1] += accX[1][i] + rh0*q1;  nd[2] += accX[2][i] + rh0*q2;
          nd[3] += accX[3][i] + rh1*q0;  nd[4] += accX[4][i] + rh1*q1;  nd[5] += accX[5][i] + rh1*q2;
          nd[6] += accX[6][i] + rh2*q0;  nd[7] += accX[7][i] + rh2*q1;  nd[8] += accX[8][i] + rh2*q2;
        }
      }

      #pragma unroll
      for (int k = 0; k < 9; k++) {
        nd[k] += __shfl_xor(nd[k], 16, 64);
        nd[k] += __shfl_xor(nd[k], 32, 64);
      }
      if (lane < 8) {
        float* o = outD + (size_t)n*72 + lane*9;
        #pragma unroll
        for (int k = 0; k < 9; k++) o[k] = 0.1f*nd[k];
      }
    }
  }
}

// ======================= scalar fallback (insurance only) =======================
__global__ __launch_bounds__(256) void fallback_all(
    const float* __restrict__ r_ij, const float* __restrict__ x_a,
    const float* __restrict__ x_v,  const float* __restrict__ x_d,
    const float* __restrict__ P000, const float* __restrict__ P110, const float* __restrict__ P220,
    const float* __restrict__ P011, const float* __restrict__ P101, const float* __restrict__ P121,
    const float* __restrict__ P211, const float* __restrict__ P111,
    const float* __restrict__ P022, const float* __restrict__ P202, const float* __restrict__ P112,
    const float* __restrict__ P222, const float* __restrict__ P212,
    const int* __restrict__ src, const int* __restrict__ dst, int E,
    float* __restrict__ outA, float* __restrict__ outV, float* __restrict__ outD)
{
  const int e = blockIdx.x*256 + threadIdx.x;
  if (e >= E) return;
  Geom g;
  if (!geom_of(r_ij, e, g)) return;
  const int nj = dst[e], ni = src[e];
  const float* xa = x_a + (size_t)nj*32;
  const float* xv = x_v + (size_t)nj*48;
  const float* xd = x_d + (size_t)nj*72;
  float V0[16],V1[16],V2[16],s1[16],T0[8],T1[8],T2[8],s2[8];
  for (int b = 0; b < 16; b++) {
    V0[b]=xv[3*b]; V1[b]=xv[3*b+1]; V2[b]=xv[3*b+2];
    s1[b]=g.h0*V0[b]+g.h1*V1[b]+g.h2*V2[b];
  }
  for (int b = 0; b < 8; b++) {
    const float* m = xd + 9*b;
    T0[b]=g.h0*m[0]+g.h1*m[3]+g.h2*m[6];
    T1[b]=g.h0*m[1]+g.h1*m[4]+g.h2*m[7];
    T2[b]=g.h0*m[2]+g.h1*m[5]+g.h2*m[8];
    s2[b]=g.h0*T0[b]+g.h1*T1[b]+g.h2*T2[b];
  }
  for (int a = 0; a < 32; a++) {
    float acc = 0;
    for (int l = 0; l < 8; l++) {
      float u = 0;
      for (int b = 0; b < 32; b++) u += P000[(a*8+l)*32+b]*xa[b];
      for (int b = 0; b < 16; b++) u += P110[(a*8+l)*16+b]*s1[b];
      for (int b = 0; b < 8;  b++) u += P220[(a*8+l)*8+b]*s2[b];
      acc += g.enc[l]*u;
    }
    atomicAdd(outA + (size_t)ni*32 + a, 0.1f*acc);
  }
  for (int v = 0; v < 16; v++) {
    float sv=0,A0=0,A1=0,A2=0,W0=0,W1=0,W2=0;
    for (int l = 0; l < 8; l++) {
      const float el = g.enc[l];
      float u=0;
      for (int b=0;b<32;b++) u += P101[(v*8+l)*32+b]*xa[b];
      for (int b=0;b<16;b++) u += P211[(v*8+l)*16+b]*s1[b];
      sv += el*u;
      float a0=0,a1=0,a2=0,w0=0,w1=0,w2=0;
      for (int b=0;b<16;b++){float p=P011[(v*8+l)*16+b]; a0+=p*V0[b];a1+=p*V1[b];a2+=p*V2[b];}
      for (int b=0;b<8;b++){float p=P121[(v*8+l)*8+b]; a0+=p*T0[b];a1+=p*T1[b];a2+=p*T2[b];}
      for (int b=0;b<16;b++){float p=P111[(v*8+l)*16+b]; w0+=p*V0[b];w1+=p*V1[b];w2+=p*V2[b];}
      A0+=el*a0;A1+=el*a1;A2+=el*a2;W0+=el*w0;W1+=el*w1;W2+=el*w2;
    }
    float* o = outV + (size_t)ni*48 + v*3;
    atomicAdd(o+0, 0.1f*(A0 + (g.h1*W2-g.h2*W1) + g.h0*sv));
    atomicAdd(o+1, 0.1f*(A1 + (g.h2*W0-g.h0*W2) + g.h1*sv));
    atomicAdd(o+2, 0.1f*(A2 + (g.h0*W1-g.h1*W0) + g.h2*sv));
  }
  const float hh[3]={g.h0,g.h1,g.h2};
  for (int d = 0; d < 8; d++) {
    float sd=0,A0=0,A1=0,A2=0,W0=0,W1=0,W2=0;
    float w[8]={0,0,0,0,0,0,0,0};
    for (int l = 0; l < 8; l++) {
      const float el = g.enc[l];
      float u=0;
      for (int b=0;b<32;b++) u += P202[(d*8+l)*32+b]*xa[b];
      sd += el*u;
      float a0=0,a1=0,a2=0,w0=0,w1=0,w2=0;
      for (int b=0;b<16;b++){float p=P112[(d*8+l)*16+b]; a0+=p*V0[b];a1+=p*V1[b];a2+=p*V2[b];}
      for (int b=0;b<8;b++){float p=P222[(d*8+l)*8+b]; a0+=p*T0[b];a1+=p*T1[b];a2+=p*T2[b];}
      for (int b=0;b<16;b++){float p=P212[(d*8+l)*16+b]; w0+=p*V0[b];w1+=p*V1[b];w2+=p*V2[b];}
      A0+=el*a0;A1+=el*a1;A2+=el*a2;W0+=el*w0;W1+=el*w1;W2+=el*w2;
      for (int b=0;b<8;b++) w[b]+=el*P022[(d*8+l)*8+b];
    }
    const float q[3] = { A0+(g.h1*W2-g.h2*W1)+g.h0*sd,
                         A1+(g.h2*W0-g.h0*W2)+g.h1*sd,
                         A2+(g.h0*W1-g.h1*W0)+g.h2*sd };
    float* o = outD + (size_t)ni*72 + d*9;
    for (int ii = 0; ii < 3; ii++)
      for (int jj = 0; jj < 3; jj++) {
        float acc = 0;
        for (int b = 0; b < 8; b++) acc += w[b]*xd[9*b + ii*3 + jj];
        atomicAdd(o + ii*3 + jj, 0.1f*(acc + hh[ii]*q[jj]));
      }
  }
}

extern "C" void kernel_launch(void* const* d_in, const int* in_sizes, int n_in,
                              void* d_out, int out_size, void* d_ws, size_t ws_size,
                              hipStream_t stream) {
  const float* r_ij = (const float*)d_in[0];
  const float* x_a  = (const float*)d_in[1];
  const float* x_v  = (const float*)d_in[2];
  const float* x_d  = (const float*)d_in[3];
  const float* P000 = (const float*)d_in[4];
  const float* P110 = (const float*)d_in[5];
  const float* P220 = (const float*)d_in[6];
  const float* P011 = (const float*)d_in[7];
  const float* P101 = (const float*)d_in[8];
  const float* P121 = (const float*)d_in[9];
  const float* P211 = (const float*)d_in[10];
  const float* P111 = (const float*)d_in[11];
  const float* P022 = (const float*)d_in[12];
  const float* P202 = (const float*)d_in[13];
  const float* P112 = (const float*)d_in[14];
  const float* P222 = (const float*)d_in[15];
  const float* P212 = (const float*)d_in[16];
  const int* src = (const int*)d_in[17];
  const int* dst = (const int*)d_in[18];

  const int E  = in_sizes[17];
  const int Nn = in_sizes[1] / 32;
  float* out  = (float*)d_out;
  float* outA = out;
  float* outV = out + (size_t)Nn*32;
  float* outD = out + (size_t)Nn*80;

  const size_t need = 4ull * (2ull*(size_t)Nn + 1 + (size_t)E);
  if (ws_size >= need) {
    int* hist    = (int*)d_ws;
    int* row_ptr = hist + Nn;
    int* sorted  = row_ptr + Nn + 1;
    hipMemsetAsync(hist, 0, (size_t)Nn*sizeof(int), stream);
    hist_k   <<<(E + 255)/256, 256, 0, stream>>>(r_ij, src, E, hist);
    scan_k   <<<1, 256, 0, stream>>>(hist, Nn, row_ptr);
    scatter_k<<<(E + 255)/256, 256, 0, stream>>>(r_ij, src, E, hist, sorted);

    const int gS = 192, gV = 288, gD = 288;   // 768 blocks = 3/CU (47KB LDS each)
    msgAll_k<<<gS + gV + gD, 256, 0, stream>>>(r_ij, x_a, x_v, x_d,
        P000, P110, P220, P011, P101, P121, P211, P111,
        P022, P202, P112, P222, P212,
        dst, row_ptr, sorted, Nn, gS, gV, outA, outV, outD);
  } else {
    hipMemsetAsync(d_out, 0, (size_t)out_size * sizeof(float), stream);
    fallback_all<<<(E + 255)/256, 256, 0, stream>>>(r_ij, x_a, x_v, x_d,
        P000, P110, P220, P011, P101, P121, P211, P111,
        P022, P202, P112, P222, P212, src, dst, E, outA, outV, outD);
  }
}